// Round 1
// 617.196 us; speedup vs baseline: 1.0540x; 1.0540x over previous
//
#include <hip/hip_runtime.h>
#include <hip/hip_bf16.h>
#include <stdint.h>

#define NN 8192
#define DD 512

typedef unsigned short u16;
typedef unsigned long long u64;
typedef __attribute__((ext_vector_type(8))) short short8;
typedef __attribute__((ext_vector_type(4))) float f32x4;

// async global->LDS, 16B per lane; LDS dest = wave-uniform base + lane*16
__device__ __forceinline__ void gld_lds16(const void* g, void* l) {
  __builtin_amdgcn_global_load_lds(
      (const __attribute__((address_space(1))) uint32_t*)(uintptr_t)g,
      (__attribute__((address_space(3))) uint32_t*)(uintptr_t)l,
      16, 0, 0);
}

__device__ __forceinline__ u16 f2bf(float f) {
  __hip_bfloat16 b = __float2bfloat16(f);
  return __builtin_bit_cast(u16, b);
}

__global__ void fill_kernel(float* __restrict__ p, int n, float v) {
  int i = blockIdx.x * 256 + threadIdx.x;
  int stride = gridDim.x * 256;
  for (; i < n; i += stride) p[i] = v;
}

__global__ void cvt4_kernel(const float4* __restrict__ src, ushort4* __restrict__ dst, int n4) {
  int i = blockIdx.x * 256 + threadIdx.x;
  int stride = gridDim.x * 256;
  for (; i < n4; i += stride) {
    float4 v = src[i];
    ushort4 o;
    o.x = f2bf(v.x); o.y = f2bf(v.y); o.z = f2bf(v.z); o.w = f2bf(v.w);
    dst[i] = o;
  }
}

// adj (int32 0/1, NN x NN) -> bitmask: u16 per 16 cols (u64 word w: bit b = col 64w+b)
// Also zeroes den[row] (one per block) - saves a launch.
__global__ void pack_adj_kernel(const int* __restrict__ adj, u16* __restrict__ mask,
                                float* __restrict__ den) {
  const int row = blockIdx.x;
  const int t = threadIdx.x;
  if (t == 0) den[row] = 0.0f;
  const uint4* arow = (const uint4*)(adj + (size_t)row * NN);
  #pragma unroll
  for (int iter = 0; iter < 2; iter++) {
    const int c16 = iter * 256 + t;
    unsigned int bits = 0;
    #pragma unroll
    for (int g = 0; g < 4; g++) {
      uint4 v = arow[c16 * 4 + g];
      bits |= (v.x ? 1u : 0u) << (g * 4 + 0);
      bits |= (v.y ? 1u : 0u) << (g * 4 + 1);
      bits |= (v.z ? 1u : 0u) << (g * 4 + 2);
      bits |= (v.w ? 1u : 0u) << (g * 4 + 3);
    }
    mask[(size_t)row * (NN / 16) + c16] = (u16)bits;
  }
}

// one wave per row: 1/||Wh_i||
__global__ void rownorm_kernel(const float* __restrict__ Wh, float* __restrict__ invn) {
  int row = blockIdx.x;
  int l = threadIdx.x;  // 64
  const float4* p = (const float4*)(Wh + (size_t)row * DD);
  float4 a = p[l], b = p[l + 64];
  float s = a.x*a.x + a.y*a.y + a.z*a.z + a.w*a.w
          + b.x*b.x + b.y*b.y + b.z*b.z + b.w*b.w;
  #pragma unroll
  for (int off = 32; off; off >>= 1) s += __shfl_down(s, off);
  if (l == 0) invn[row] = 1.0f / sqrtf(s);
}

// 64x64 tile: U = bf16(Wh * invn) (row-major) and WhT = bf16(Wh)^T
__global__ void u_wht_kernel(const float* __restrict__ Wh, const float* __restrict__ invn,
                             u16* __restrict__ U, u16* __restrict__ WhT) {
  __shared__ float tile[64][65];
  int i0 = blockIdx.x * 64, d0 = blockIdx.y * 64;
  int c = threadIdx.x & 63, rb = threadIdx.x >> 6;
  #pragma unroll
  for (int r = rb; r < 64; r += 4) {
    float v = Wh[(size_t)(i0 + r) * DD + d0 + c];
    tile[r][c] = v;
    U[(size_t)(i0 + r) * DD + d0 + c] = f2bf(v * invn[i0 + r]);
  }
  __syncthreads();
  #pragma unroll
  for (int r = rb; r < 64; r += 4) {
    WhT[(size_t)(d0 + r) * NN + i0 + c] = f2bf(tile[c][r]);
  }
}

// Wh-GEMM: C = A * B^T fp32, A:[M x K], B:[Nn x K] bf16. 128x128 tile, 256 thr.
__global__ void __launch_bounds__(256) gemm_wh(
    const u16* __restrict__ A, const u16* __restrict__ B,
    int Nn, int K, float* __restrict__ Cf)
{
  __shared__ __align__(16) u16 As[128 * 32];
  __shared__ __align__(16) u16 Bs[128 * 32];

  const int tid = threadIdx.x;
  const int w = tid >> 6;
  const int lane = tid & 63;
  const int lm = lane & 15;
  const int q = lane >> 4;
  const int row0 = blockIdx.y * 128;
  const int col0 = blockIdx.x * 128;
  const int RM = (w >> 1) * 64;
  const int RN = (w & 1) * 64;
  const int sr = tid >> 2;
  const int sk = (tid & 3) * 8;

  f32x4 acc[4][4];
  #pragma unroll
  for (int a_ = 0; a_ < 4; a_++)
    #pragma unroll
    for (int b_ = 0; b_ < 4; b_++)
      acc[a_][b_] = (f32x4){0.f, 0.f, 0.f, 0.f};

  const size_t Abase = (size_t)row0 * K;
  const size_t Bbase = (size_t)col0 * K;

  for (int k0 = 0; k0 < K; k0 += 32) {
    __syncthreads();
    gld_lds16(A + Abase + (size_t)sr * K + k0 + sk,        (char*)As + w * 1024);
    gld_lds16(A + Abase + (size_t)(sr + 64) * K + k0 + sk, (char*)As + 4096 + w * 1024);
    gld_lds16(B + Bbase + (size_t)sr * K + k0 + sk,        (char*)Bs + w * 1024);
    gld_lds16(B + Bbase + (size_t)(sr + 64) * K + k0 + sk, (char*)Bs + 4096 + w * 1024);
    __syncthreads();

    short8 af[4], bfr[4];
    #pragma unroll
    for (int mt = 0; mt < 4; mt++)
      af[mt] = *(const short8*)&As[(RM + mt * 16 + lm) * 32 + q * 8];
    #pragma unroll
    for (int nt = 0; nt < 4; nt++)
      bfr[nt] = *(const short8*)&Bs[(RN + nt * 16 + lm) * 32 + q * 8];

    #pragma unroll
    for (int mt = 0; mt < 4; mt++)
      #pragma unroll
      for (int nt = 0; nt < 4; nt++)
        acc[mt][nt] = __builtin_amdgcn_mfma_f32_16x16x32_bf16(af[mt], bfr[nt], acc[mt][nt], 0, 0, 0);
  }

  #pragma unroll
  for (int mt = 0; mt < 4; mt++) {
    const int ib = row0 + RM + mt * 16 + q * 4;
    #pragma unroll
    for (int rr = 0; rr < 4; rr++) {
      const int i = ib + rr;
      #pragma unroll
      for (int nt = 0; nt < 4; nt++) {
        const int jc = col0 + RN + nt * 16 + lm;
        Cf[(size_t)i * Nn + jc] = acc[mt][nt][rr];
      }
    }
  }
}

// Symmetric sim-GEMM: S = U U^T computed only for lower-tri 128x128 blocks
// (bi >= bj, 2080 blocks). Each off-diag block writes P[i][j] (normal) and
// P[j][i] (mirror, ushort4-coalesced along rows) + den atomics for both sides.
__global__ void __launch_bounds__(256) gemm_sim(
    const u16* __restrict__ U, const u64* __restrict__ maskw,
    u16* __restrict__ Pb, float* __restrict__ den)
{
  __shared__ __align__(16) u16 As[128 * 32];
  __shared__ __align__(16) u16 Bs[128 * 32];

  // decode linear block index -> lower-tri (bi, bj), bi >= bj
  const int b = blockIdx.x;
  int bi = (int)((sqrtf(8.0f * (float)b + 1.0f) - 1.0f) * 0.5f);
  while ((bi + 1) * (bi + 2) / 2 <= b) bi++;
  while (bi * (bi + 1) / 2 > b) bi--;
  const int bj = b - bi * (bi + 1) / 2;

  const int tid = threadIdx.x;
  const int w = tid >> 6;
  const int lane = tid & 63;
  const int lm = lane & 15;
  const int q = lane >> 4;
  const int row0 = bi * 128;
  const int col0 = bj * 128;
  const int RM = (w >> 1) * 64;
  const int RN = (w & 1) * 64;
  const int sr = tid >> 2;
  const int sk = (tid & 3) * 8;
  const bool diag = (bi == bj);

  f32x4 acc[4][4];
  #pragma unroll
  for (int a_ = 0; a_ < 4; a_++)
    #pragma unroll
    for (int b_ = 0; b_ < 4; b_++)
      acc[a_][b_] = (f32x4){0.f, 0.f, 0.f, 0.f};

  const size_t Abase = (size_t)row0 * DD;
  const size_t Bbase = (size_t)col0 * DD;

  for (int k0 = 0; k0 < DD; k0 += 32) {
    __syncthreads();
    gld_lds16(U + Abase + (size_t)sr * DD + k0 + sk,        (char*)As + w * 1024);
    gld_lds16(U + Abase + (size_t)(sr + 64) * DD + k0 + sk, (char*)As + 4096 + w * 1024);
    gld_lds16(U + Bbase + (size_t)sr * DD + k0 + sk,        (char*)Bs + w * 1024);
    gld_lds16(U + Bbase + (size_t)(sr + 64) * DD + k0 + sk, (char*)Bs + 4096 + w * 1024);
    __syncthreads();

    short8 af[4], bfr[4];
    #pragma unroll
    for (int mt = 0; mt < 4; mt++)
      af[mt] = *(const short8*)&As[(RM + mt * 16 + lm) * 32 + q * 8];
    #pragma unroll
    for (int nt = 0; nt < 4; nt++)
      bfr[nt] = *(const short8*)&Bs[(RN + nt * 16 + lm) * 32 + q * 8];

    #pragma unroll
    for (int mt = 0; mt < 4; mt++)
      #pragma unroll
      for (int nt = 0; nt < 4; nt++)
        acc[mt][nt] = __builtin_amdgcn_mfma_f32_16x16x32_bf16(af[mt], bfr[nt], acc[mt][nt], 0, 0, 0);
  }

  // C/D layout: col = lane&15 (lm), row = q*4 + reg (rr)
  const int wordIdx = (col0 + RN) >> 6;        // mask word for normal side
  const int word2Idx = (row0 + RM) >> 6;       // mask word for mirror side

  // preload mirror mask words (per nt; uniform across mt/rr/q)
  u64 wrd2[4];
  if (!diag) {
    #pragma unroll
    for (int nt = 0; nt < 4; nt++) {
      const int jc = col0 + RN + nt * 16 + lm;
      wrd2[nt] = maskw[(size_t)jc * (NN / 64) + word2Idx];
    }
  }

  float msum[4] = {0.f, 0.f, 0.f, 0.f};

  #pragma unroll
  for (int mt = 0; mt < 4; mt++) {
    const int ib = row0 + RM + mt * 16 + q * 4;
    float pm[4][4];  // [nt][rr] mirror values
    #pragma unroll
    for (int rr = 0; rr < 4; rr++) {
      const int i = ib + rr;
      const u64 wrd = maskw[(size_t)i * (NN / 64) + wordIdx];
      const int bit2 = mt * 16 + q * 4 + rr;   // == i & 63
      float psum = 0.f;
      #pragma unroll
      for (int nt = 0; nt < 4; nt++) {
        const int jc = col0 + RN + nt * 16 + lm;
        const float ev = __expf(acc[mt][nt][rr]);
        const bool on = ((wrd >> (nt * 16 + lm)) & 1ull) || (diag && i == jc);
        const float p = on ? ev : 0.0f;
        psum += p;
        Pb[(size_t)i * NN + jc] = f2bf(p);
        if (!diag) {
          const bool on2 = (wrd2[nt] >> bit2) & 1ull;
          const float pmv = on2 ? ev : 0.0f;
          pm[nt][rr] = pmv;
          msum[nt] += pmv;
        }
      }
      #pragma unroll
      for (int off = 8; off; off >>= 1) psum += __shfl_down(psum, off, 16);
      if (lm == 0) atomicAdd(&den[i], psum);
    }
    if (!diag) {
      #pragma unroll
      for (int nt = 0; nt < 4; nt++) {
        const int jc = col0 + RN + nt * 16 + lm;
        ushort4 m4;
        m4.x = f2bf(pm[nt][0]); m4.y = f2bf(pm[nt][1]);
        m4.z = f2bf(pm[nt][2]); m4.w = f2bf(pm[nt][3]);
        *(ushort4*)&Pb[(size_t)jc * NN + ib] = m4;
      }
    }
  }

  if (!diag) {
    #pragma unroll
    for (int nt = 0; nt < 4; nt++) {
      float s = msum[nt];
      s += __shfl_xor(s, 16);
      s += __shfl_xor(s, 32);
      if (q == 0) atomicAdd(&den[col0 + RN + nt * 16 + lm], s);
    }
  }
}

// out-GEMM v2: 256x256 tile, BK=32, 8 waves (2M x 4N), split-K=4 via blockIdx.z.
// Phase-split schedule (T3/T4): per K-tile two phases, counted s_waitcnt vmcnt(4)
// (tile t+2's 4 staging loads stay in flight across barriers, never drained to 0
// in steady state), XOR chunk swizzle (T2: slot = c ^ ((r>>1)&3), pre-swizzled
// global source + swizzled ds_read -> 2-way conflicts = free), setprio around
// each 16-MFMA cluster (T5). 64 KB LDS double-buffer (2 x 32 KB K-tile buffers).
__global__ void __launch_bounds__(512, 2) gemm_out2(
    const u16* __restrict__ P_,   // P [NN x NN]
    const u16* __restrict__ Wt,   // WhT [DD x NN]
    u16* __restrict__ p0, u16* __restrict__ p1,
    u16* __restrict__ p2, u16* __restrict__ p3)
{
  __shared__ __align__(16) char lds[65536];  // buf b at b*32768: A 16KB | B 16KB

  const int tid = threadIdx.x;
  const int lane = tid & 63;
  const int lm = lane & 15;
  const int q = lane >> 4;
  const int w = tid >> 6;       // 0..7
  const int wm = w >> 2;        // 0..1 -> 128 rows
  const int wn = w & 3;         // 0..3 -> 64 cols
  const int row0 = blockIdx.x * 256;   // i block
  const int col0 = blockIdx.y * 256;   // d block
  const int z = blockIdx.z;            // split-K
  const int kBegin = z * (NN / 4);
  const int NT = (NN / 4) / 32;        // 64 K-tiles

  const u16* Ab = P_ + (size_t)row0 * NN;
  const u16* Bb = Wt + (size_t)col0 * NN;

  // staging: 512 threads cover one 128-row half per gld (rows tid>>2, slot tid&3).
  // content chunk = slot ^ ((row>>1)&3)  (inverse of the read-side swizzle)
  const int srow = tid >> 2;                                  // 0..127
  const int sch8 = (((tid & 3) ^ ((tid >> 3) & 3)) << 3);     // element offset
  const int wofs = (tid >> 6) << 10;                          // per-wave LDS base

  // read-side: logical (r, chunk c) lives at byte r*64 + ((c ^ ((r>>1)&3))<<4).
  // (r>>1)&3 is invariant under r += 16, so fold it once.
  const int rA = wm * 128 + lm;
  const int rB = wn * 64 + lm;
  const int aoff = rA * 64 + ((q ^ ((rA >> 1) & 3)) << 4);
  const int boff = 16384 + rB * 64 + ((q ^ ((rB >> 1) & 3)) << 4);

  f32x4 acc[8][4];
  #pragma unroll
  for (int m = 0; m < 8; m++)
    #pragma unroll
    for (int n = 0; n < 4; n++)
      acc[m][n] = (f32x4){0.f, 0.f, 0.f, 0.f};

#define STAGE4(koff, dstoff)                                                      \
  do {                                                                            \
    char* d_ = lds + (dstoff);                                                    \
    gld_lds16(Ab + (size_t)srow * NN + (koff) + sch8,         d_ + wofs);         \
    gld_lds16(Ab + (size_t)(srow + 128) * NN + (koff) + sch8, d_ + 8192 + wofs);  \
    gld_lds16(Bb + (size_t)srow * NN + (koff) + sch8,         d_ + 16384 + wofs); \
    gld_lds16(Bb + (size_t)(srow + 128) * NN + (koff) + sch8, d_ + 24576 + wofs); \
  } while (0)

  // prologue: tile 0 -> buf0, tile 1 -> buf1; drain tile 0, leave tile 1 in flight
  STAGE4(kBegin, 0);
  STAGE4(kBegin + 32, 32768);
  asm volatile("s_waitcnt vmcnt(4)" ::: "memory");
  asm volatile("s_barrier" ::: "memory");

  // Per K-tile T (buffer CBOFF = (T&1)*32768):
  //  ph0: 12 ds_read_b128 (A m0..7, B n0..3); bar; lgkmcnt(0); 16 MFMA (m0..3); bar
  //  ph1: stage tile T+2 -> same buffer (its tile-T reads all completed before
  //       ph0's closing barrier, enforced by the lgkmcnt(0)); bar; 16 MFMA
  //       (m4..7); vmcnt(4) drains tile T+1's loads, leaves T+2's 4; bar
#define TILE(T, CBOFF)                                                            \
  do {                                                                            \
    const char* cb = lds + (CBOFF);                                               \
    short8 af[8], bf_[4];                                                         \
    _Pragma("unroll")                                                             \
    for (int m = 0; m < 8; m++)                                                   \
      af[m] = *(const short8*)(cb + aoff + m * 1024);                             \
    _Pragma("unroll")                                                             \
    for (int n = 0; n < 4; n++)                                                   \
      bf_[n] = *(const short8*)(cb + boff + n * 1024);                            \
    asm volatile("s_barrier" ::: "memory");                                       \
    asm volatile("s_waitcnt lgkmcnt(0)" ::: "memory");                            \
    __builtin_amdgcn_s_setprio(1);                                                \
    _Pragma("unroll")                                                             \
    for (int m = 0; m < 4; m++)                                                   \
      _Pragma("unroll")                                                           \
      for (int n = 0; n < 4; n++)                                                 \
        acc[m][n] = __builtin_amdgcn_mfma_f32_16x16x32_bf16(af[m], bf_[n], acc[m][n], 0, 0, 0); \
    __builtin_amdgcn_s_setprio(0);                                                \
    asm volatile("s_barrier" ::: "memory");                                       \
    if ((T) + 2 < NT) STAGE4(kBegin + ((T) + 2) * 32, CBOFF);                     \
    asm volatile("s_barrier" ::: "memory");                                       \
    __builtin_amdgcn_s_setprio(1);                                                \
    _Pragma("unroll")                                                             \
    for (int m = 4; m < 8; m++)                                                   \
      _Pragma("unroll")                                                           \
      for (int n = 0; n < 4; n++)                                                 \
        acc[m][n] = __builtin_amdgcn_mfma_f32_16x16x32_bf16(af[m], bf_[n], acc[m][n], 0, 0, 0); \
    __builtin_amdgcn_s_setprio(0);                                                \
    if ((T) + 2 < NT) { asm volatile("s_waitcnt vmcnt(4)" ::: "memory"); }        \
    else              { asm volatile("s_waitcnt vmcnt(0)" ::: "memory"); }        \
    asm volatile("s_barrier" ::: "memory");                                       \
  } while (0)

  #pragma unroll 1
  for (int t = 0; t < NT; t += 2) {
    TILE(t, 0);
    TILE(t + 1, 32768);
  }
#undef TILE
#undef STAGE4

  u16* const part = (z == 0) ? p0 : (z == 1) ? p1 : (z == 2) ? p2 : p3;
  #pragma unroll
  for (int m = 0; m < 8; m++) {
    const int ib = row0 + wm * 128 + m * 16 + q * 4;
    #pragma unroll
    for (int rr = 0; rr < 4; rr++) {
      const int i = ib + rr;
      #pragma unroll
      for (int n = 0; n < 4; n++) {
        const int dc = col0 + wn * 64 + n * 16 + lm;
        part[(size_t)i * DD + dc] = f2bf(acc[m][n][rr]);
      }
    }
  }
}

// out = (sum of 4 bf16 partials) / den[row]; each thread handles 8 cols
__global__ void reduce4_kernel(const uint4* __restrict__ p0, const uint4* __restrict__ p1,
                               const uint4* __restrict__ p2, const uint4* __restrict__ p3,
                               const float* __restrict__ den, float4* __restrict__ out) {
  const int idx = blockIdx.x * 256 + threadIdx.x;   // NN*DD/8 units of 8 cols
  const int row = idx >> 6;                          // 64 units per row
  const float dinv = 1.0f / den[row];
  float s[8] = {0, 0, 0, 0, 0, 0, 0, 0};
  #pragma unroll
  for (int zp = 0; zp < 4; zp++) {
    const uint4 u = (zp == 0 ? p0 : zp == 1 ? p1 : zp == 2 ? p2 : p3)[idx];
    s[0] += __uint_as_float(u.x << 16); s[1] += __uint_as_float(u.x & 0xffff0000u);
    s[2] += __uint_as_float(u.y << 16); s[3] += __uint_as_float(u.y & 0xffff0000u);
    s[4] += __uint_as_float(u.z << 16); s[5] += __uint_as_float(u.z & 0xffff0000u);
    s[6] += __uint_as_float(u.w << 16); s[7] += __uint_as_float(u.w & 0xffff0000u);
  }
  float4 o0 = {s[0] * dinv, s[1] * dinv, s[2] * dinv, s[3] * dinv};
  float4 o1 = {s[4] * dinv, s[5] * dinv, s[6] * dinv, s[7] * dinv};
  out[idx * 2] = o0;
  out[idx * 2 + 1] = o1;
}

extern "C" void kernel_launch(void* const* d_in, const int* in_sizes, int n_in,
                              void* d_out, int out_size, void* d_ws, size_t ws_size,
                              hipStream_t stream) {
  const float* h = (const float*)d_in[0];
  const int* adj = (const int*)d_in[1];
  const float* W = (const float*)d_in[2];
  float* out = (float*)d_out;

  const size_t SZ_P    = (size_t)NN * NN * 2;      // 134.2 MB
  const size_t SZ_MASK = (size_t)NN * NN / 8;      // 8.4 MB  (-> part0)
  const size_t SZ_WHT  = (size_t)DD * NN * 2;      // 8.4 MB
  const size_t SZ_HB   = (size_t)NN * DD * 2;      // 8.4 MB  (-> part2)
  const size_t SZ_WB   = (size_t)DD * DD * 2;      // 0.5 MB
  const size_t SZ_U    = (size_t)NN * DD * 2;      // 8.4 MB  (-> part1)
  const size_t SZ_P3   = (size_t)NN * DD * 2;      // 8.4 MB  (part3)
  const size_t NEEDED  = SZ_P + SZ_MASK + SZ_WHT + SZ_HB + SZ_WB + SZ_U + SZ_P3 + 2 * (size_t)NN * 4;

  if (ws_size < NEEDED) {
    fill_kernel<<<256, 256, 0, stream>>>(out, out_size, 12345.0f);
    return;
  }

  char* ws = (char*)d_ws;
  size_t off = 0;
  u16*   P    = (u16*)(ws + off); off += SZ_P;
  u16*   mask = (u16*)(ws + off); off += SZ_MASK;
  u16*   WhT  = (u16*)(ws + off); off += SZ_WHT;
  u16*   hb   = (u16*)(ws + off); off += SZ_HB;
  u16*   Wb   = (u16*)(ws + off); off += SZ_WB;
  u16*   U    = (u16*)(ws + off); off += SZ_U;
  u16*   p3   = (u16*)(ws + off); off += SZ_P3;
  float* invn = (float*)(ws + off);
  float* den  = invn + NN;

  // Wh fp32 (16.8 MB) aliases the P prefix: dead before sim writes P.
  float* Wh = (float*)P;
  // split-K partials reuse regions dead after the sim-GEMM:
  u16* part0 = mask;
  u16* part1 = U;
  u16* part2 = hb;
  u16* part3 = p3;

  pack_adj_kernel<<<NN, 256, 0, stream>>>(adj, mask, den);
  cvt4_kernel<<<1024, 256, 0, stream>>>((const float4*)h, (ushort4*)hb, NN * DD / 4);
  cvt4_kernel<<<256, 256, 0, stream>>>((const float4*)W, (ushort4*)Wb, DD * DD / 4);
  // Wh = h @ W^T
  gemm_wh<<<dim3(DD / 128, NN / 128), 256, 0, stream>>>(hb, Wb, DD, DD, Wh);
  rownorm_kernel<<<NN, 64, 0, stream>>>(Wh, invn);
  u_wht_kernel<<<dim3(NN / 64, DD / 64), 256, 0, stream>>>(Wh, invn, U, WhT);
  // P = mask ? exp(U U^T) : 0 (bf16), symmetric lower-tri + mirror, fused den
  gemm_sim<<<64 * 65 / 2, 256, 0, stream>>>(U, (const u64*)mask, P, den);
  // out partials: 256x256 tile, phase-split counted-vmcnt schedule, split-K=4
  gemm_out2<<<dim3(NN / 256, DD / 256, 4), 512, 0, stream>>>(P, WhT, part0, part1, part2, part3);
  // out = (p0+p1+p2+p3) / den
  reduce4_kernel<<<NN * DD / 8 / 256, 256, 0, stream>>>(
      (const uint4*)part0, (const uint4*)part1, (const uint4*)part2, (const uint4*)part3,
      den, (float4*)out);
}

// Round 2
// 607.040 us; speedup vs baseline: 1.0716x; 1.0167x over previous
//
#include <hip/hip_runtime.h>
#include <hip/hip_bf16.h>
#include <stdint.h>

#define NN 8192
#define DD 512

typedef unsigned short u16;
typedef unsigned long long u64;
typedef __attribute__((ext_vector_type(8))) short short8;
typedef __attribute__((ext_vector_type(4))) float f32x4;

// async global->LDS, 16B per lane; LDS dest = wave-uniform base + lane*16
__device__ __forceinline__ void gld_lds16(const void* g, void* l) {
  __builtin_amdgcn_global_load_lds(
      (const __attribute__((address_space(1))) uint32_t*)(uintptr_t)g,
      (__attribute__((address_space(3))) uint32_t*)(uintptr_t)l,
      16, 0, 0);
}

__device__ __forceinline__ u16 f2bf(float f) {
  __hip_bfloat16 b = __float2bfloat16(f);
  return __builtin_bit_cast(u16, b);
}

__global__ void fill_kernel(float* __restrict__ p, int n, float v) {
  int i = blockIdx.x * 256 + threadIdx.x;
  int stride = gridDim.x * 256;
  for (; i < n; i += stride) p[i] = v;
}

__global__ void cvt4_kernel(const float4* __restrict__ src, ushort4* __restrict__ dst, int n4) {
  int i = blockIdx.x * 256 + threadIdx.x;
  int stride = gridDim.x * 256;
  for (; i < n4; i += stride) {
    float4 v = src[i];
    ushort4 o;
    o.x = f2bf(v.x); o.y = f2bf(v.y); o.z = f2bf(v.z); o.w = f2bf(v.w);
    dst[i] = o;
  }
}

// adj (int32 0/1, NN x NN) -> bitmask: u16 per 16 cols (u64 word w: bit b = col 64w+b)
// Also zeroes den[row] (one per block) - saves a launch.
__global__ void pack_adj_kernel(const int* __restrict__ adj, u16* __restrict__ mask,
                                float* __restrict__ den) {
  const int row = blockIdx.x;
  const int t = threadIdx.x;
  if (t == 0) den[row] = 0.0f;
  const uint4* arow = (const uint4*)(adj + (size_t)row * NN);
  #pragma unroll
  for (int iter = 0; iter < 2; iter++) {
    const int c16 = iter * 256 + t;
    unsigned int bits = 0;
    #pragma unroll
    for (int g = 0; g < 4; g++) {
      uint4 v = arow[c16 * 4 + g];
      bits |= (v.x ? 1u : 0u) << (g * 4 + 0);
      bits |= (v.y ? 1u : 0u) << (g * 4 + 1);
      bits |= (v.z ? 1u : 0u) << (g * 4 + 2);
      bits |= (v.w ? 1u : 0u) << (g * 4 + 3);
    }
    mask[(size_t)row * (NN / 16) + c16] = (u16)bits;
  }
}

// one wave per row: 1/||Wh_i||
__global__ void rownorm_kernel(const float* __restrict__ Wh, float* __restrict__ invn) {
  int row = blockIdx.x;
  int l = threadIdx.x;  // 64
  const float4* p = (const float4*)(Wh + (size_t)row * DD);
  float4 a = p[l], b = p[l + 64];
  float s = a.x*a.x + a.y*a.y + a.z*a.z + a.w*a.w
          + b.x*b.x + b.y*b.y + b.z*b.z + b.w*b.w;
  #pragma unroll
  for (int off = 32; off; off >>= 1) s += __shfl_down(s, off);
  if (l == 0) invn[row] = 1.0f / sqrtf(s);
}

// 64x64 tile: U = bf16(Wh * invn) (row-major) and WhT = bf16(Wh)^T
__global__ void u_wht_kernel(const float* __restrict__ Wh, const float* __restrict__ invn,
                             u16* __restrict__ U, u16* __restrict__ WhT) {
  __shared__ float tile[64][65];
  int i0 = blockIdx.x * 64, d0 = blockIdx.y * 64;
  int c = threadIdx.x & 63, rb = threadIdx.x >> 6;
  #pragma unroll
  for (int r = rb; r < 64; r += 4) {
    float v = Wh[(size_t)(i0 + r) * DD + d0 + c];
    tile[r][c] = v;
    U[(size_t)(i0 + r) * DD + d0 + c] = f2bf(v * invn[i0 + r]);
  }
  __syncthreads();
  #pragma unroll
  for (int r = rb; r < 64; r += 4) {
    WhT[(size_t)(d0 + r) * NN + i0 + c] = f2bf(tile[c][r]);
  }
}

// Wh-GEMM: C = A * B^T fp32, A:[M x K], B:[Nn x K] bf16. 128x128 tile, 256 thr.
__global__ void __launch_bounds__(256) gemm_wh(
    const u16* __restrict__ A, const u16* __restrict__ B,
    int Nn, int K, float* __restrict__ Cf)
{
  __shared__ __align__(16) u16 As[128 * 32];
  __shared__ __align__(16) u16 Bs[128 * 32];

  const int tid = threadIdx.x;
  const int w = tid >> 6;
  const int lane = tid & 63;
  const int lm = lane & 15;
  const int q = lane >> 4;
  const int row0 = blockIdx.y * 128;
  const int col0 = blockIdx.x * 128;
  const int RM = (w >> 1) * 64;
  const int RN = (w & 1) * 64;
  const int sr = tid >> 2;
  const int sk = (tid & 3) * 8;

  f32x4 acc[4][4];
  #pragma unroll
  for (int a_ = 0; a_ < 4; a_++)
    #pragma unroll
    for (int b_ = 0; b_ < 4; b_++)
      acc[a_][b_] = (f32x4){0.f, 0.f, 0.f, 0.f};

  const size_t Abase = (size_t)row0 * K;
  const size_t Bbase = (size_t)col0 * K;

  for (int k0 = 0; k0 < K; k0 += 32) {
    __syncthreads();
    gld_lds16(A + Abase + (size_t)sr * K + k0 + sk,        (char*)As + w * 1024);
    gld_lds16(A + Abase + (size_t)(sr + 64) * K + k0 + sk, (char*)As + 4096 + w * 1024);
    gld_lds16(B + Bbase + (size_t)sr * K + k0 + sk,        (char*)Bs + w * 1024);
    gld_lds16(B + Bbase + (size_t)(sr + 64) * K + k0 + sk, (char*)Bs + 4096 + w * 1024);
    __syncthreads();

    short8 af[4], bfr[4];
    #pragma unroll
    for (int mt = 0; mt < 4; mt++)
      af[mt] = *(const short8*)&As[(RM + mt * 16 + lm) * 32 + q * 8];
    #pragma unroll
    for (int nt = 0; nt < 4; nt++)
      bfr[nt] = *(const short8*)&Bs[(RN + nt * 16 + lm) * 32 + q * 8];

    #pragma unroll
    for (int mt = 0; mt < 4; mt++)
      #pragma unroll
      for (int nt = 0; nt < 4; nt++)
        acc[mt][nt] = __builtin_amdgcn_mfma_f32_16x16x32_bf16(af[mt], bfr[nt], acc[mt][nt], 0, 0, 0);
  }

  #pragma unroll
  for (int mt = 0; mt < 4; mt++) {
    const int ib = row0 + RM + mt * 16 + q * 4;
    #pragma unroll
    for (int rr = 0; rr < 4; rr++) {
      const int i = ib + rr;
      #pragma unroll
      for (int nt = 0; nt < 4; nt++) {
        const int jc = col0 + RN + nt * 16 + lm;
        Cf[(size_t)i * Nn + jc] = acc[mt][nt][rr];
      }
    }
  }
}

// Symmetric sim-GEMM v2: S = U U^T for lower-tri 128x128 blocks (2080 blocks).
// Main loop ported to the TILE schedule proven on gemm_out2 (round 0):
// double-buffered 32 KB LDS, XOR chunk swizzle (slot = c ^ ((r>>1)&3), applied
// to BOTH the staging source and the ds_read -> residual 2-way conflict = free),
// two 8-MFMA phases per 32-K tile with STAGE(T+2) between them, counted
// s_waitcnt vmcnt(4) (never 0 in steady state), setprio around MFMA clusters.
// Epilogue (mask/exp/atomics/mirror) unchanged from v1.
__global__ void __launch_bounds__(256) gemm_sim(
    const u16* __restrict__ U, const u64* __restrict__ maskw,
    u16* __restrict__ Pb, float* __restrict__ den)
{
  __shared__ __align__(16) char lds[32768];  // buf b at b*16384: A 8KB | B 8KB

  // decode linear block index -> lower-tri (bi, bj), bi >= bj
  const int b = blockIdx.x;
  int bi = (int)((sqrtf(8.0f * (float)b + 1.0f) - 1.0f) * 0.5f);
  while ((bi + 1) * (bi + 2) / 2 <= b) bi++;
  while (bi * (bi + 1) / 2 > b) bi--;
  const int bj = b - bi * (bi + 1) / 2;

  const int tid = threadIdx.x;
  const int w = tid >> 6;
  const int lane = tid & 63;
  const int lm = lane & 15;
  const int q = lane >> 4;
  const int row0 = bi * 128;
  const int col0 = bj * 128;
  const int RM = (w >> 1) * 64;
  const int RN = (w & 1) * 64;
  const bool diag = (bi == bj);

  const u16* Ab = U + (size_t)row0 * DD;
  const u16* Bb = U + (size_t)col0 * DD;

  // staging: 256 threads cover 64 rows per gld (row tid>>2, slot tid&3);
  // source content chunk = slot ^ ((row>>1)&3)  (row>>1 == tid>>3)
  const int srow = tid >> 2;                                  // 0..63
  const int sch8 = (((tid & 3) ^ ((tid >> 3) & 3)) << 3);     // element offset
  const int wofs = w << 10;                                   // per-wave LDS base

  // read-side: logical (r, chunk c) lives at byte r*64 + ((c ^ ((r>>1)&3))<<4);
  // (r>>1)&3 invariant under r += 16, fold once.
  const int rA = RM + lm;
  const int rB = RN + lm;
  const int aoff = rA * 64 + ((q ^ ((rA >> 1) & 3)) << 4);
  const int boff = 8192 + rB * 64 + ((q ^ ((rB >> 1) & 3)) << 4);

  f32x4 acc[4][4];
  #pragma unroll
  for (int a_ = 0; a_ < 4; a_++)
    #pragma unroll
    for (int b_ = 0; b_ < 4; b_++)
      acc[a_][b_] = (f32x4){0.f, 0.f, 0.f, 0.f};

#define SSTAGE(koff, dstoff)                                                      \
  do {                                                                            \
    char* d_ = lds + (dstoff);                                                    \
    gld_lds16(Ab + (size_t)srow * DD + (koff) + sch8,        d_ + wofs);          \
    gld_lds16(Ab + (size_t)(srow + 64) * DD + (koff) + sch8, d_ + 4096 + wofs);   \
    gld_lds16(Bb + (size_t)srow * DD + (koff) + sch8,        d_ + 8192 + wofs);   \
    gld_lds16(Bb + (size_t)(srow + 64) * DD + (koff) + sch8, d_ + 12288 + wofs);  \
  } while (0)

  // prologue: tile 0 -> buf0, tile 1 -> buf1; drain tile 0, leave tile 1 in flight
  SSTAGE(0, 0);
  SSTAGE(32, 16384);
  asm volatile("s_waitcnt vmcnt(4)" ::: "memory");
  asm volatile("s_barrier" ::: "memory");

#define STILE(T, CBOFF)                                                           \
  do {                                                                            \
    const char* cb = lds + (CBOFF);                                               \
    short8 af[4], bfr[4];                                                         \
    _Pragma("unroll")                                                             \
    for (int m = 0; m < 4; m++)                                                   \
      af[m] = *(const short8*)(cb + aoff + m * 1024);                             \
    _Pragma("unroll")                                                             \
    for (int n = 0; n < 4; n++)                                                   \
      bfr[n] = *(const short8*)(cb + boff + n * 1024);                            \
    asm volatile("s_barrier" ::: "memory");                                       \
    asm volatile("s_waitcnt lgkmcnt(0)" ::: "memory");                            \
    __builtin_amdgcn_s_setprio(1);                                                \
    _Pragma("unroll")                                                             \
    for (int m = 0; m < 2; m++)                                                   \
      _Pragma("unroll")                                                           \
      for (int n = 0; n < 4; n++)                                                 \
        acc[m][n] = __builtin_amdgcn_mfma_f32_16x16x32_bf16(af[m], bfr[n], acc[m][n], 0, 0, 0); \
    __builtin_amdgcn_s_setprio(0);                                                \
    asm volatile("s_barrier" ::: "memory");                                       \
    if ((T) + 2 < 16) SSTAGE(((T) + 2) * 32, CBOFF);                              \
    asm volatile("s_barrier" ::: "memory");                                       \
    __builtin_amdgcn_s_setprio(1);                                                \
    _Pragma("unroll")                                                             \
    for (int m = 2; m < 4; m++)                                                   \
      _Pragma("unroll")                                                           \
      for (int n = 0; n < 4; n++)                                                 \
        acc[m][n] = __builtin_amdgcn_mfma_f32_16x16x32_bf16(af[m], bfr[n], acc[m][n], 0, 0, 0); \
    __builtin_amdgcn_s_setprio(0);                                                \
    if ((T) + 2 < 16) { asm volatile("s_waitcnt vmcnt(4)" ::: "memory"); }        \
    else              { asm volatile("s_waitcnt vmcnt(0)" ::: "memory"); }        \
    asm volatile("s_barrier" ::: "memory");                                       \
  } while (0)

  #pragma unroll 1
  for (int t = 0; t < 16; t += 2) {
    STILE(t, 0);
    STILE(t + 1, 16384);
  }
#undef STILE
#undef SSTAGE

  // C/D layout: col = lane&15 (lm), row = q*4 + reg (rr)
  const int wordIdx = (col0 + RN) >> 6;        // mask word for normal side
  const int word2Idx = (row0 + RM) >> 6;       // mask word for mirror side

  // preload mirror mask words (per nt; uniform across mt/rr/q)
  u64 wrd2[4];
  if (!diag) {
    #pragma unroll
    for (int nt = 0; nt < 4; nt++) {
      const int jc = col0 + RN + nt * 16 + lm;
      wrd2[nt] = maskw[(size_t)jc * (NN / 64) + word2Idx];
    }
  }

  float msum[4] = {0.f, 0.f, 0.f, 0.f};

  #pragma unroll
  for (int mt = 0; mt < 4; mt++) {
    const int ib = row0 + RM + mt * 16 + q * 4;
    float pm[4][4];  // [nt][rr] mirror values
    #pragma unroll
    for (int rr = 0; rr < 4; rr++) {
      const int i = ib + rr;
      const u64 wrd = maskw[(size_t)i * (NN / 64) + wordIdx];
      const int bit2 = mt * 16 + q * 4 + rr;   // == i & 63
      float psum = 0.f;
      #pragma unroll
      for (int nt = 0; nt < 4; nt++) {
        const int jc = col0 + RN + nt * 16 + lm;
        const float ev = __expf(acc[mt][nt][rr]);
        const bool on = ((wrd >> (nt * 16 + lm)) & 1ull) || (diag && i == jc);
        const float p = on ? ev : 0.0f;
        psum += p;
        Pb[(size_t)i * NN + jc] = f2bf(p);
        if (!diag) {
          const bool on2 = (wrd2[nt] >> bit2) & 1ull;
          const float pmv = on2 ? ev : 0.0f;
          pm[nt][rr] = pmv;
          msum[nt] += pmv;
        }
      }
      #pragma unroll
      for (int off = 8; off; off >>= 1) psum += __shfl_down(psum, off, 16);
      if (lm == 0) atomicAdd(&den[i], psum);
    }
    if (!diag) {
      #pragma unroll
      for (int nt = 0; nt < 4; nt++) {
        const int jc = col0 + RN + nt * 16 + lm;
        ushort4 m4;
        m4.x = f2bf(pm[nt][0]); m4.y = f2bf(pm[nt][1]);
        m4.z = f2bf(pm[nt][2]); m4.w = f2bf(pm[nt][3]);
        *(ushort4*)&Pb[(size_t)jc * NN + ib] = m4;
      }
    }
  }

  if (!diag) {
    #pragma unroll
    for (int nt = 0; nt < 4; nt++) {
      float s = msum[nt];
      s += __shfl_xor(s, 16);
      s += __shfl_xor(s, 32);
      if (q == 0) atomicAdd(&den[col0 + RN + nt * 16 + lm], s);
    }
  }
}

// out-GEMM v2: 256x256 tile, BK=32, 8 waves (2M x 4N), split-K=4 via blockIdx.z.
// Phase-split schedule (T3/T4): per K-tile two phases, counted s_waitcnt vmcnt(4)
// (tile t+2's 4 staging loads stay in flight across barriers, never drained to 0
// in steady state), XOR chunk swizzle (T2: slot = c ^ ((r>>1)&3), pre-swizzled
// global source + swizzled ds_read -> 2-way conflicts = free), setprio around
// each 16-MFMA cluster (T5). 64 KB LDS double-buffer (2 x 32 KB K-tile buffers).
__global__ void __launch_bounds__(512, 2) gemm_out2(
    const u16* __restrict__ P_,   // P [NN x NN]
    const u16* __restrict__ Wt,   // WhT [DD x NN]
    u16* __restrict__ p0, u16* __restrict__ p1,
    u16* __restrict__ p2, u16* __restrict__ p3)
{
  __shared__ __align__(16) char lds[65536];  // buf b at b*32768: A 16KB | B 16KB

  const int tid = threadIdx.x;
  const int lane = tid & 63;
  const int lm = lane & 15;
  const int q = lane >> 4;
  const int w = tid >> 6;       // 0..7
  const int wm = w >> 2;        // 0..1 -> 128 rows
  const int wn = w & 3;         // 0..3 -> 64 cols
  const int row0 = blockIdx.x * 256;   // i block
  const int col0 = blockIdx.y * 256;   // d block
  const int z = blockIdx.z;            // split-K
  const int kBegin = z * (NN / 4);
  const int NT = (NN / 4) / 32;        // 64 K-tiles

  const u16* Ab = P_ + (size_t)row0 * NN;
  const u16* Bb = Wt + (size_t)col0 * NN;

  // staging: 512 threads cover one 128-row half per gld (rows tid>>2, slot tid&3).
  // content chunk = slot ^ ((row>>1)&3)  (inverse of the read-side swizzle)
  const int srow = tid >> 2;                                  // 0..127
  const int sch8 = (((tid & 3) ^ ((tid >> 3) & 3)) << 3);     // element offset
  const int wofs = (tid >> 6) << 10;                          // per-wave LDS base

  // read-side: logical (r, chunk c) lives at byte r*64 + ((c ^ ((r>>1)&3))<<4).
  // (r>>1)&3 is invariant under r += 16, so fold it once.
  const int rA = wm * 128 + lm;
  const int rB = wn * 64 + lm;
  const int aoff = rA * 64 + ((q ^ ((rA >> 1) & 3)) << 4);
  const int boff = 16384 + rB * 64 + ((q ^ ((rB >> 1) & 3)) << 4);

  f32x4 acc[8][4];
  #pragma unroll
  for (int m = 0; m < 8; m++)
    #pragma unroll
    for (int n = 0; n < 4; n++)
      acc[m][n] = (f32x4){0.f, 0.f, 0.f, 0.f};

#define STAGE4(koff, dstoff)                                                      \
  do {                                                                            \
    char* d_ = lds + (dstoff);                                                    \
    gld_lds16(Ab + (size_t)srow * NN + (koff) + sch8,         d_ + wofs);         \
    gld_lds16(Ab + (size_t)(srow + 128) * NN + (koff) + sch8, d_ + 8192 + wofs);  \
    gld_lds16(Bb + (size_t)srow * NN + (koff) + sch8,         d_ + 16384 + wofs); \
    gld_lds16(Bb + (size_t)(srow + 128) * NN + (koff) + sch8, d_ + 24576 + wofs); \
  } while (0)

  // prologue: tile 0 -> buf0, tile 1 -> buf1; drain tile 0, leave tile 1 in flight
  STAGE4(kBegin, 0);
  STAGE4(kBegin + 32, 32768);
  asm volatile("s_waitcnt vmcnt(4)" ::: "memory");
  asm volatile("s_barrier" ::: "memory");

  // Per K-tile T (buffer CBOFF = (T&1)*32768):
  //  ph0: 12 ds_read_b128 (A m0..7, B n0..3); bar; lgkmcnt(0); 16 MFMA (m0..3); bar
  //  ph1: stage tile T+2 -> same buffer (its tile-T reads all completed before
  //       ph0's closing barrier, enforced by the lgkmcnt(0)); bar; 16 MFMA
  //       (m4..7); vmcnt(4) drains tile T+1's loads, leaves T+2's 4; bar
#define TILE(T, CBOFF)                                                            \
  do {                                                                            \
    const char* cb = lds + (CBOFF);                                               \
    short8 af[8], bf_[4];                                                         \
    _Pragma("unroll")                                                             \
    for (int m = 0; m < 8; m++)                                                   \
      af[m] = *(const short8*)(cb + aoff + m * 1024);                             \
    _Pragma("unroll")                                                             \
    for (int n = 0; n < 4; n++)                                                   \
      bf_[n] = *(const short8*)(cb + boff + n * 1024);                            \
    asm volatile("s_barrier" ::: "memory");                                       \
    asm volatile("s_waitcnt lgkmcnt(0)" ::: "memory");                            \
    __builtin_amdgcn_s_setprio(1);                                                \
    _Pragma("unroll")                                                             \
    for (int m = 0; m < 4; m++)                                                   \
      _Pragma("unroll")                                                           \
      for (int n = 0; n < 4; n++)                                                 \
        acc[m][n] = __builtin_amdgcn_mfma_f32_16x16x32_bf16(af[m], bf_[n], acc[m][n], 0, 0, 0); \
    __builtin_amdgcn_s_setprio(0);                                                \
    asm volatile("s_barrier" ::: "memory");                                       \
    if ((T) + 2 < NT) STAGE4(kBegin + ((T) + 2) * 32, CBOFF);                     \
    asm volatile("s_barrier" ::: "memory");                                       \
    __builtin_amdgcn_s_setprio(1);                                                \
    _Pragma("unroll")                                                             \
    for (int m = 4; m < 8; m++)                                                   \
      _Pragma("unroll")                                                           \
      for (int n = 0; n < 4; n++)                                                 \
        acc[m][n] = __builtin_amdgcn_mfma_f32_16x16x32_bf16(af[m], bf_[n], acc[m][n], 0, 0, 0); \
    __builtin_amdgcn_s_setprio(0);                                                \
    if ((T) + 2 < NT) { asm volatile("s_waitcnt vmcnt(4)" ::: "memory"); }        \
    else              { asm volatile("s_waitcnt vmcnt(0)" ::: "memory"); }        \
    asm volatile("s_barrier" ::: "memory");                                       \
  } while (0)

  #pragma unroll 1
  for (int t = 0; t < NT; t += 2) {
    TILE(t, 0);
    TILE(t + 1, 32768);
  }
#undef TILE
#undef STAGE4

  u16* const part = (z == 0) ? p0 : (z == 1) ? p1 : (z == 2) ? p2 : p3;
  #pragma unroll
  for (int m = 0; m < 8; m++) {
    const int ib = row0 + wm * 128 + m * 16 + q * 4;
    #pragma unroll
    for (int rr = 0; rr < 4; rr++) {
      const int i = ib + rr;
      #pragma unroll
      for (int n = 0; n < 4; n++) {
        const int dc = col0 + wn * 64 + n * 16 + lm;
        part[(size_t)i * DD + dc] = f2bf(acc[m][n][rr]);
      }
    }
  }
}

// out = (sum of 4 bf16 partials) / den[row]; each thread handles 8 cols
__global__ void reduce4_kernel(const uint4* __restrict__ p0, const uint4* __restrict__ p1,
                               const uint4* __restrict__ p2, const uint4* __restrict__ p3,
                               const float* __restrict__ den, float4* __restrict__ out) {
  const int idx = blockIdx.x * 256 + threadIdx.x;   // NN*DD/8 units of 8 cols
  const int row = idx >> 6;                          // 64 units per row
  const float dinv = 1.0f / den[row];
  float s[8] = {0, 0, 0, 0, 0, 0, 0, 0};
  #pragma unroll
  for (int zp = 0; zp < 4; zp++) {
    const uint4 u = (zp == 0 ? p0 : zp == 1 ? p1 : zp == 2 ? p2 : p3)[idx];
    s[0] += __uint_as_float(u.x << 16); s[1] += __uint_as_float(u.x & 0xffff0000u);
    s[2] += __uint_as_float(u.y << 16); s[3] += __uint_as_float(u.y & 0xffff0000u);
    s[4] += __uint_as_float(u.z << 16); s[5] += __uint_as_float(u.z & 0xffff0000u);
    s[6] += __uint_as_float(u.w << 16); s[7] += __uint_as_float(u.w & 0xffff0000u);
  }
  float4 o0 = {s[0] * dinv, s[1] * dinv, s[2] * dinv, s[3] * dinv};
  float4 o1 = {s[4] * dinv, s[5] * dinv, s[6] * dinv, s[7] * dinv};
  out[idx * 2] = o0;
  out[idx * 2 + 1] = o1;
}

extern "C" void kernel_launch(void* const* d_in, const int* in_sizes, int n_in,
                              void* d_out, int out_size, void* d_ws, size_t ws_size,
                              hipStream_t stream) {
  const float* h = (const float*)d_in[0];
  const int* adj = (const int*)d_in[1];
  const float* W = (const float*)d_in[2];
  float* out = (float*)d_out;

  const size_t SZ_P    = (size_t)NN * NN * 2;      // 134.2 MB
  const size_t SZ_MASK = (size_t)NN * NN / 8;      // 8.4 MB  (-> part0)
  const size_t SZ_WHT  = (size_t)DD * NN * 2;      // 8.4 MB
  const size_t SZ_HB   = (size_t)NN * DD * 2;      // 8.4 MB  (-> part2)
  const size_t SZ_WB   = (size_t)DD * DD * 2;      // 0.5 MB
  const size_t SZ_U    = (size_t)NN * DD * 2;      // 8.4 MB  (-> part1)
  const size_t SZ_P3   = (size_t)NN * DD * 2;      // 8.4 MB  (part3)
  const size_t NEEDED  = SZ_P + SZ_MASK + SZ_WHT + SZ_HB + SZ_WB + SZ_U + SZ_P3 + 2 * (size_t)NN * 4;

  if (ws_size < NEEDED) {
    fill_kernel<<<256, 256, 0, stream>>>(out, out_size, 12345.0f);
    return;
  }

  char* ws = (char*)d_ws;
  size_t off = 0;
  u16*   P    = (u16*)(ws + off); off += SZ_P;
  u16*   mask = (u16*)(ws + off); off += SZ_MASK;
  u16*   WhT  = (u16*)(ws + off); off += SZ_WHT;
  u16*   hb   = (u16*)(ws + off); off += SZ_HB;
  u16*   Wb   = (u16*)(ws + off); off += SZ_WB;
  u16*   U    = (u16*)(ws + off); off += SZ_U;
  u16*   p3   = (u16*)(ws + off); off += SZ_P3;
  float* invn = (float*)(ws + off);
  float* den  = invn + NN;

  // Wh fp32 (16.8 MB) aliases the P prefix: dead before sim writes P.
  float* Wh = (float*)P;
  // split-K partials reuse regions dead after the sim-GEMM:
  u16* part0 = mask;
  u16* part1 = U;
  u16* part2 = hb;
  u16* part3 = p3;

  pack_adj_kernel<<<NN, 256, 0, stream>>>(adj, mask, den);
  cvt4_kernel<<<1024, 256, 0, stream>>>((const float4*)h, (ushort4*)hb, NN * DD / 4);
  cvt4_kernel<<<256, 256, 0, stream>>>((const float4*)W, (ushort4*)Wb, DD * DD / 4);
  // Wh = h @ W^T
  gemm_wh<<<dim3(DD / 128, NN / 128), 256, 0, stream>>>(hb, Wb, DD, DD, Wh);
  rownorm_kernel<<<NN, 64, 0, stream>>>(Wh, invn);
  u_wht_kernel<<<dim3(NN / 64, DD / 64), 256, 0, stream>>>(Wh, invn, U, WhT);
  // P = mask ? exp(U U^T) : 0 (bf16), symmetric lower-tri + mirror, fused den
  gemm_sim<<<64 * 65 / 2, 256, 0, stream>>>(U, (const u64*)mask, P, den);
  // out partials: 256x256 tile, phase-split counted-vmcnt schedule, split-K=4
  gemm_out2<<<dim3(NN / 256, DD / 256, 4), 512, 0, stream>>>(P, WhT, part0, part1, part2, part3);
  // out = (p0+p1+p2+p3) / den
  reduce4_kernel<<<NN * DD / 8 / 256, 256, 0, stream>>>(
      (const uint4*)part0, (const uint4*)part1, (const uint4*)part2, (const uint4*)part3,
      den, (float4*)out);
}

// Round 3
// 579.841 us; speedup vs baseline: 1.1219x; 1.0469x over previous
//
#include <hip/hip_runtime.h>
#include <hip/hip_bf16.h>
#include <stdint.h>

#define NN 8192
#define DD 512

typedef unsigned short u16;
typedef unsigned long long u64;
typedef __attribute__((ext_vector_type(8))) short short8;
typedef __attribute__((ext_vector_type(4))) float f32x4;

// async global->LDS, 16B per lane; LDS dest = wave-uniform base + lane*16
__device__ __forceinline__ void gld_lds16(const void* g, void* l) {
  __builtin_amdgcn_global_load_lds(
      (const __attribute__((address_space(1))) uint32_t*)(uintptr_t)g,
      (__attribute__((address_space(3))) uint32_t*)(uintptr_t)l,
      16, 0, 0);
}

__device__ __forceinline__ u16 f2bf(float f) {
  __hip_bfloat16 b = __float2bfloat16(f);
  return __builtin_bit_cast(u16, b);
}

__global__ void fill_kernel(float* __restrict__ p, int n, float v) {
  int i = blockIdx.x * 256 + threadIdx.x;
  int stride = gridDim.x * 256;
  for (; i < n; i += stride) p[i] = v;
}

__global__ void cvt4_kernel(const float4* __restrict__ src, ushort4* __restrict__ dst, int n4) {
  int i = blockIdx.x * 256 + threadIdx.x;
  int stride = gridDim.x * 256;
  for (; i < n4; i += stride) {
    float4 v = src[i];
    ushort4 o;
    o.x = f2bf(v.x); o.y = f2bf(v.y); o.z = f2bf(v.z); o.w = f2bf(v.w);
    dst[i] = o;
  }
}

// one wave per row: 1/||Wh_i||; also zeroes den[row] (pack_adj is gone)
__global__ void rownorm_kernel(const float* __restrict__ Wh, float* __restrict__ invn,
                               float* __restrict__ den) {
  int row = blockIdx.x;
  int l = threadIdx.x;  // 64
  const float4* p = (const float4*)(Wh + (size_t)row * DD);
  float4 a = p[l], b = p[l + 64];
  float s = a.x*a.x + a.y*a.y + a.z*a.z + a.w*a.w
          + b.x*b.x + b.y*b.y + b.z*b.z + b.w*b.w;
  #pragma unroll
  for (int off = 32; off; off >>= 1) s += __shfl_down(s, off);
  if (l == 0) {
    invn[row] = 1.0f / sqrtf(s);
    den[row] = 0.0f;
  }
}

// 64x64 tile: U = bf16(Wh * invn) (row-major) and WhT = bf16(Wh)^T
__global__ void u_wht_kernel(const float* __restrict__ Wh, const float* __restrict__ invn,
                             u16* __restrict__ U, u16* __restrict__ WhT) {
  __shared__ float tile[64][65];
  int i0 = blockIdx.x * 64, d0 = blockIdx.y * 64;
  int c = threadIdx.x & 63, rb = threadIdx.x >> 6;
  #pragma unroll
  for (int r = rb; r < 64; r += 4) {
    float v = Wh[(size_t)(i0 + r) * DD + d0 + c];
    tile[r][c] = v;
    U[(size_t)(i0 + r) * DD + d0 + c] = f2bf(v * invn[i0 + r]);
  }
  __syncthreads();
  #pragma unroll
  for (int r = rb; r < 64; r += 4) {
    WhT[(size_t)(d0 + r) * NN + i0 + c] = f2bf(tile[c][r]);
  }
}

// Wh-GEMM: C = A * B^T fp32, A:[M x K], B:[Nn x K] bf16. 128x128 tile, 256 thr.
__global__ void __launch_bounds__(256) gemm_wh(
    const u16* __restrict__ A, const u16* __restrict__ B,
    int Nn, int K, float* __restrict__ Cf)
{
  __shared__ __align__(16) u16 As[128 * 32];
  __shared__ __align__(16) u16 Bs[128 * 32];

  const int tid = threadIdx.x;
  const int w = tid >> 6;
  const int lane = tid & 63;
  const int lm = lane & 15;
  const int q = lane >> 4;
  const int row0 = blockIdx.y * 128;
  const int col0 = blockIdx.x * 128;
  const int RM = (w >> 1) * 64;
  const int RN = (w & 1) * 64;
  const int sr = tid >> 2;
  const int sk = (tid & 3) * 8;

  f32x4 acc[4][4];
  #pragma unroll
  for (int a_ = 0; a_ < 4; a_++)
    #pragma unroll
    for (int b_ = 0; b_ < 4; b_++)
      acc[a_][b_] = (f32x4){0.f, 0.f, 0.f, 0.f};

  const size_t Abase = (size_t)row0 * K;
  const size_t Bbase = (size_t)col0 * K;

  for (int k0 = 0; k0 < K; k0 += 32) {
    __syncthreads();
    gld_lds16(A + Abase + (size_t)sr * K + k0 + sk,        (char*)As + w * 1024);
    gld_lds16(A + Abase + (size_t)(sr + 64) * K + k0 + sk, (char*)As + 4096 + w * 1024);
    gld_lds16(B + Bbase + (size_t)sr * K + k0 + sk,        (char*)Bs + w * 1024);
    gld_lds16(B + Bbase + (size_t)(sr + 64) * K + k0 + sk, (char*)Bs + 4096 + w * 1024);
    __syncthreads();

    short8 af[4], bfr[4];
    #pragma unroll
    for (int mt = 0; mt < 4; mt++)
      af[mt] = *(const short8*)&As[(RM + mt * 16 + lm) * 32 + q * 8];
    #pragma unroll
    for (int nt = 0; nt < 4; nt++)
      bfr[nt] = *(const short8*)&Bs[(RN + nt * 16 + lm) * 32 + q * 8];

    #pragma unroll
    for (int mt = 0; mt < 4; mt++)
      #pragma unroll
      for (int nt = 0; nt < 4; nt++)
        acc[mt][nt] = __builtin_amdgcn_mfma_f32_16x16x32_bf16(af[mt], bfr[nt], acc[mt][nt], 0, 0, 0);
  }

  #pragma unroll
  for (int mt = 0; mt < 4; mt++) {
    const int ib = row0 + RM + mt * 16 + q * 4;
    #pragma unroll
    for (int rr = 0; rr < 4; rr++) {
      const int i = ib + rr;
      #pragma unroll
      for (int nt = 0; nt < 4; nt++) {
        const int jc = col0 + RN + nt * 16 + lm;
        Cf[(size_t)i * Nn + jc] = acc[mt][nt][rr];
      }
    }
  }
}

// Symmetric sim-GEMM v3: S = U U^T for lower-tri 128x128 blocks (2080 blocks).
// Main loop: TILE schedule (dbuf LDS, XOR chunk swizzle both-sides, counted
// vmcnt(4), setprio). Epilogue now reads adj int32 DIRECTLY (pack_adj pass is
// eliminated; same 268 MB total traffic, all 64B-sector-granular, overlapped
// with this kernel's compute instead of a dedicated serial streaming pass).
__global__ void __launch_bounds__(256) gemm_sim(
    const u16* __restrict__ U, const int* __restrict__ adj,
    u16* __restrict__ Pb, float* __restrict__ den)
{
  __shared__ __align__(16) char lds[32768];  // buf b at b*16384: A 8KB | B 8KB

  // decode linear block index -> lower-tri (bi, bj), bi >= bj
  const int b = blockIdx.x;
  int bi = (int)((sqrtf(8.0f * (float)b + 1.0f) - 1.0f) * 0.5f);
  while ((bi + 1) * (bi + 2) / 2 <= b) bi++;
  while (bi * (bi + 1) / 2 > b) bi--;
  const int bj = b - bi * (bi + 1) / 2;

  const int tid = threadIdx.x;
  const int w = tid >> 6;
  const int lane = tid & 63;
  const int lm = lane & 15;
  const int q = lane >> 4;
  const int row0 = bi * 128;
  const int col0 = bj * 128;
  const int RM = (w >> 1) * 64;
  const int RN = (w & 1) * 64;
  const bool diag = (bi == bj);

  const u16* Ab = U + (size_t)row0 * DD;
  const u16* Bb = U + (size_t)col0 * DD;

  // staging: 256 threads cover 64 rows per gld (row tid>>2, slot tid&3);
  // source content chunk = slot ^ ((row>>1)&3)  (row>>1 == tid>>3)
  const int srow = tid >> 2;                                  // 0..63
  const int sch8 = (((tid & 3) ^ ((tid >> 3) & 3)) << 3);     // element offset
  const int wofs = w << 10;                                   // per-wave LDS base

  // read-side: logical (r, chunk c) lives at byte r*64 + ((c ^ ((r>>1)&3))<<4);
  // (r>>1)&3 invariant under r += 16, fold once.
  const int rA = RM + lm;
  const int rB = RN + lm;
  const int aoff = rA * 64 + ((q ^ ((rA >> 1) & 3)) << 4);
  const int boff = 8192 + rB * 64 + ((q ^ ((rB >> 1) & 3)) << 4);

  f32x4 acc[4][4];
  #pragma unroll
  for (int a_ = 0; a_ < 4; a_++)
    #pragma unroll
    for (int b_ = 0; b_ < 4; b_++)
      acc[a_][b_] = (f32x4){0.f, 0.f, 0.f, 0.f};

#define SSTAGE(koff, dstoff)                                                      \
  do {                                                                            \
    char* d_ = lds + (dstoff);                                                    \
    gld_lds16(Ab + (size_t)srow * DD + (koff) + sch8,        d_ + wofs);          \
    gld_lds16(Ab + (size_t)(srow + 64) * DD + (koff) + sch8, d_ + 4096 + wofs);   \
    gld_lds16(Bb + (size_t)srow * DD + (koff) + sch8,        d_ + 8192 + wofs);   \
    gld_lds16(Bb + (size_t)(srow + 64) * DD + (koff) + sch8, d_ + 12288 + wofs);  \
  } while (0)

  // prologue: tile 0 -> buf0, tile 1 -> buf1; drain tile 0, leave tile 1 in flight
  SSTAGE(0, 0);
  SSTAGE(32, 16384);
  asm volatile("s_waitcnt vmcnt(4)" ::: "memory");
  asm volatile("s_barrier" ::: "memory");

#define STILE(T, CBOFF)                                                           \
  do {                                                                            \
    const char* cb = lds + (CBOFF);                                               \
    short8 af[4], bfr[4];                                                         \
    _Pragma("unroll")                                                             \
    for (int m = 0; m < 4; m++)                                                   \
      af[m] = *(const short8*)(cb + aoff + m * 1024);                             \
    _Pragma("unroll")                                                             \
    for (int n = 0; n < 4; n++)                                                   \
      bfr[n] = *(const short8*)(cb + boff + n * 1024);                            \
    asm volatile("s_barrier" ::: "memory");                                       \
    asm volatile("s_waitcnt lgkmcnt(0)" ::: "memory");                            \
    __builtin_amdgcn_s_setprio(1);                                                \
    _Pragma("unroll")                                                             \
    for (int m = 0; m < 2; m++)                                                   \
      _Pragma("unroll")                                                           \
      for (int n = 0; n < 4; n++)                                                 \
        acc[m][n] = __builtin_amdgcn_mfma_f32_16x16x32_bf16(af[m], bfr[n], acc[m][n], 0, 0, 0); \
    __builtin_amdgcn_s_setprio(0);                                                \
    asm volatile("s_barrier" ::: "memory");                                       \
    if ((T) + 2 < 16) SSTAGE(((T) + 2) * 32, CBOFF);                              \
    asm volatile("s_barrier" ::: "memory");                                       \
    __builtin_amdgcn_s_setprio(1);                                                \
    _Pragma("unroll")                                                             \
    for (int m = 2; m < 4; m++)                                                   \
      _Pragma("unroll")                                                           \
      for (int n = 0; n < 4; n++)                                                 \
        acc[m][n] = __builtin_amdgcn_mfma_f32_16x16x32_bf16(af[m], bfr[n], acc[m][n], 0, 0, 0); \
    __builtin_amdgcn_s_setprio(0);                                                \
    if ((T) + 2 < 16) { asm volatile("s_waitcnt vmcnt(4)" ::: "memory"); }        \
    else              { asm volatile("s_waitcnt vmcnt(0)" ::: "memory"); }        \
    asm volatile("s_barrier" ::: "memory");                                       \
  } while (0)

  #pragma unroll 1
  for (int t = 0; t < 16; t += 2) {
    STILE(t, 0);
    STILE(t + 1, 16384);
  }
#undef STILE
#undef SSTAGE

  // C/D layout: col = lane&15 (lm), row = q*4 + reg (rr)
  float msum[4] = {0.f, 0.f, 0.f, 0.f};

  #pragma unroll
  for (int mt = 0; mt < 4; mt++) {
    const int ibase = row0 + RM + mt * 16 + q * 4;

    // --- adj loads for this mt batch (issued up-front, coalesced 64B sectors) ---
    // normal side: na[rr][nt] = adj[ibase+rr][col0+RN+nt*16+lm]
    int na[4][4];
    #pragma unroll
    for (int rr = 0; rr < 4; rr++)
      #pragma unroll
      for (int nt = 0; nt < 4; nt++)
        na[rr][nt] = adj[(size_t)(ibase + rr) * NN + col0 + RN + nt * 16 + lm];
    // mirror side: ma[nt] = adj[jc][ibase .. ibase+3] (uint4, 16B aligned)
    uint4 ma[4];
    if (!diag) {
      #pragma unroll
      for (int nt = 0; nt < 4; nt++)
        ma[nt] = *(const uint4*)&adj[(size_t)(col0 + RN + nt * 16 + lm) * NN + ibase];
    }

    float pm[4][4];  // [nt][rr] mirror values
    #pragma unroll
    for (int rr = 0; rr < 4; rr++) {
      const int i = ibase + rr;
      float psum = 0.f;
      #pragma unroll
      for (int nt = 0; nt < 4; nt++) {
        const int jc = col0 + RN + nt * 16 + lm;
        const float ev = __expf(acc[mt][nt][rr]);
        const bool on = (na[rr][nt] != 0) || (diag && i == jc);
        const float p = on ? ev : 0.0f;
        psum += p;
        Pb[(size_t)i * NN + jc] = f2bf(p);
        if (!diag) {
          const unsigned mv = (rr == 0) ? ma[nt].x : (rr == 1) ? ma[nt].y
                            : (rr == 2) ? ma[nt].z : ma[nt].w;
          const float pmv = (mv != 0u) ? ev : 0.0f;
          pm[nt][rr] = pmv;
          msum[nt] += pmv;
        }
      }
      #pragma unroll
      for (int off = 8; off; off >>= 1) psum += __shfl_down(psum, off, 16);
      if (lm == 0) atomicAdd(&den[i], psum);
    }
    if (!diag) {
      #pragma unroll
      for (int nt = 0; nt < 4; nt++) {
        const int jc = col0 + RN + nt * 16 + lm;
        ushort4 m4;
        m4.x = f2bf(pm[nt][0]); m4.y = f2bf(pm[nt][1]);
        m4.z = f2bf(pm[nt][2]); m4.w = f2bf(pm[nt][3]);
        *(ushort4*)&Pb[(size_t)jc * NN + ibase] = m4;
      }
    }
  }

  if (!diag) {
    #pragma unroll
    for (int nt = 0; nt < 4; nt++) {
      float s = msum[nt];
      s += __shfl_xor(s, 16);
      s += __shfl_xor(s, 32);
      if (q == 0) atomicAdd(&den[col0 + RN + nt * 16 + lm], s);
    }
  }
}

// out-GEMM v2: 256x256 tile, BK=32, 8 waves (2M x 4N), split-K=4 via blockIdx.z.
// Phase-split schedule (T3/T4): per K-tile two phases, counted s_waitcnt vmcnt(4)
// (tile t+2's 4 staging loads stay in flight across barriers, never drained to 0
// in steady state), XOR chunk swizzle (T2: slot = c ^ ((r>>1)&3), pre-swizzled
// global source + swizzled ds_read -> 2-way conflicts = free), setprio around
// each 16-MFMA cluster (T5). 64 KB LDS double-buffer (2 x 32 KB K-tile buffers).
__global__ void __launch_bounds__(512, 2) gemm_out2(
    const u16* __restrict__ P_,   // P [NN x NN]
    const u16* __restrict__ Wt,   // WhT [DD x NN]
    u16* __restrict__ p0, u16* __restrict__ p1,
    u16* __restrict__ p2, u16* __restrict__ p3)
{
  __shared__ __align__(16) char lds[65536];  // buf b at b*32768: A 16KB | B 16KB

  const int tid = threadIdx.x;
  const int lane = tid & 63;
  const int lm = lane & 15;
  const int q = lane >> 4;
  const int w = tid >> 6;       // 0..7
  const int wm = w >> 2;        // 0..1 -> 128 rows
  const int wn = w & 3;         // 0..3 -> 64 cols
  const int row0 = blockIdx.x * 256;   // i block
  const int col0 = blockIdx.y * 256;   // d block
  const int z = blockIdx.z;            // split-K
  const int kBegin = z * (NN / 4);
  const int NT = (NN / 4) / 32;        // 64 K-tiles

  const u16* Ab = P_ + (size_t)row0 * NN;
  const u16* Bb = Wt + (size_t)col0 * NN;

  // staging: 512 threads cover one 128-row half per gld (rows tid>>2, slot tid&3).
  // content chunk = slot ^ ((row>>1)&3)  (inverse of the read-side swizzle)
  const int srow = tid >> 2;                                  // 0..127
  const int sch8 = (((tid & 3) ^ ((tid >> 3) & 3)) << 3);     // element offset
  const int wofs = (tid >> 6) << 10;                          // per-wave LDS base

  // read-side: logical (r, chunk c) lives at byte r*64 + ((c ^ ((r>>1)&3))<<4).
  // (r>>1)&3 is invariant under r += 16, so fold it once.
  const int rA = wm * 128 + lm;
  const int rB = wn * 64 + lm;
  const int aoff = rA * 64 + ((q ^ ((rA >> 1) & 3)) << 4);
  const int boff = 16384 + rB * 64 + ((q ^ ((rB >> 1) & 3)) << 4);

  f32x4 acc[8][4];
  #pragma unroll
  for (int m = 0; m < 8; m++)
    #pragma unroll
    for (int n = 0; n < 4; n++)
      acc[m][n] = (f32x4){0.f, 0.f, 0.f, 0.f};

#define STAGE4(koff, dstoff)                                                      \
  do {                                                                            \
    char* d_ = lds + (dstoff);                                                    \
    gld_lds16(Ab + (size_t)srow * NN + (koff) + sch8,         d_ + wofs);         \
    gld_lds16(Ab + (size_t)(srow + 128) * NN + (koff) + sch8, d_ + 8192 + wofs);  \
    gld_lds16(Bb + (size_t)srow * NN + (koff) + sch8,         d_ + 16384 + wofs); \
    gld_lds16(Bb + (size_t)(srow + 128) * NN + (koff) + sch8, d_ + 24576 + wofs); \
  } while (0)

  // prologue: tile 0 -> buf0, tile 1 -> buf1; drain tile 0, leave tile 1 in flight
  STAGE4(kBegin, 0);
  STAGE4(kBegin + 32, 32768);
  asm volatile("s_waitcnt vmcnt(4)" ::: "memory");
  asm volatile("s_barrier" ::: "memory");

  // Per K-tile T (buffer CBOFF = (T&1)*32768):
  //  ph0: 12 ds_read_b128 (A m0..7, B n0..3); bar; lgkmcnt(0); 16 MFMA (m0..3); bar
  //  ph1: stage tile T+2 -> same buffer (its tile-T reads all completed before
  //       ph0's closing barrier, enforced by the lgkmcnt(0)); bar; 16 MFMA
  //       (m4..7); vmcnt(4) drains tile T+1's loads, leaves T+2's 4; bar
#define TILE(T, CBOFF)                                                            \
  do {                                                                            \
    const char* cb = lds + (CBOFF);                                               \
    short8 af[8], bf_[4];                                                         \
    _Pragma("unroll")                                                             \
    for (int m = 0; m < 8; m++)                                                   \
      af[m] = *(const short8*)(cb + aoff + m * 1024);                             \
    _Pragma("unroll")                                                             \
    for (int n = 0; n < 4; n++)                                                   \
      bf_[n] = *(const short8*)(cb + boff + n * 1024);                            \
    asm volatile("s_barrier" ::: "memory");                                       \
    asm volatile("s_waitcnt lgkmcnt(0)" ::: "memory");                            \
    __builtin_amdgcn_s_setprio(1);                                                \
    _Pragma("unroll")                                                             \
    for (int m = 0; m < 4; m++)                                                   \
      _Pragma("unroll")                                                           \
      for (int n = 0; n < 4; n++)                                                 \
        acc[m][n] = __builtin_amdgcn_mfma_f32_16x16x32_bf16(af[m], bf_[n], acc[m][n], 0, 0, 0); \
    __builtin_amdgcn_s_setprio(0);                                                \
    asm volatile("s_barrier" ::: "memory");                                       \
    if ((T) + 2 < NT) STAGE4(kBegin + ((T) + 2) * 32, CBOFF);                     \
    asm volatile("s_barrier" ::: "memory");                                       \
    __builtin_amdgcn_s_setprio(1);                                                \
    _Pragma("unroll")                                                             \
    for (int m = 4; m < 8; m++)                                                   \
      _Pragma("unroll")                                                           \
      for (int n = 0; n < 4; n++)                                                 \
        acc[m][n] = __builtin_amdgcn_mfma_f32_16x16x32_bf16(af[m], bf_[n], acc[m][n], 0, 0, 0); \
    __builtin_amdgcn_s_setprio(0);                                                \
    if ((T) + 2 < NT) { asm volatile("s_waitcnt vmcnt(4)" ::: "memory"); }        \
    else              { asm volatile("s_waitcnt vmcnt(0)" ::: "memory"); }        \
    asm volatile("s_barrier" ::: "memory");                                       \
  } while (0)

  #pragma unroll 1
  for (int t = 0; t < NT; t += 2) {
    TILE(t, 0);
    TILE(t + 1, 32768);
  }
#undef TILE
#undef STAGE4

  u16* const part = (z == 0) ? p0 : (z == 1) ? p1 : (z == 2) ? p2 : p3;
  #pragma unroll
  for (int m = 0; m < 8; m++) {
    const int ib = row0 + wm * 128 + m * 16 + q * 4;
    #pragma unroll
    for (int rr = 0; rr < 4; rr++) {
      const int i = ib + rr;
      #pragma unroll
      for (int n = 0; n < 4; n++) {
        const int dc = col0 + wn * 64 + n * 16 + lm;
        part[(size_t)i * DD + dc] = f2bf(acc[m][n][rr]);
      }
    }
  }
}

// out = (sum of 4 bf16 partials) / den[row]; each thread handles 8 cols
__global__ void reduce4_kernel(const uint4* __restrict__ p0, const uint4* __restrict__ p1,
                               const uint4* __restrict__ p2, const uint4* __restrict__ p3,
                               const float* __restrict__ den, float4* __restrict__ out) {
  const int idx = blockIdx.x * 256 + threadIdx.x;   // NN*DD/8 units of 8 cols
  const int row = idx >> 6;                          // 64 units per row
  const float dinv = 1.0f / den[row];
  float s[8] = {0, 0, 0, 0, 0, 0, 0, 0};
  #pragma unroll
  for (int zp = 0; zp < 4; zp++) {
    const uint4 u = (zp == 0 ? p0 : zp == 1 ? p1 : zp == 2 ? p2 : p3)[idx];
    s[0] += __uint_as_float(u.x << 16); s[1] += __uint_as_float(u.x & 0xffff0000u);
    s[2] += __uint_as_float(u.y << 16); s[3] += __uint_as_float(u.y & 0xffff0000u);
    s[4] += __uint_as_float(u.z << 16); s[5] += __uint_as_float(u.z & 0xffff0000u);
    s[6] += __uint_as_float(u.w << 16); s[7] += __uint_as_float(u.w & 0xffff0000u);
  }
  float4 o0 = {s[0] * dinv, s[1] * dinv, s[2] * dinv, s[3] * dinv};
  float4 o1 = {s[4] * dinv, s[5] * dinv, s[6] * dinv, s[7] * dinv};
  out[idx * 2] = o0;
  out[idx * 2 + 1] = o1;
}

extern "C" void kernel_launch(void* const* d_in, const int* in_sizes, int n_in,
                              void* d_out, int out_size, void* d_ws, size_t ws_size,
                              hipStream_t stream) {
  const float* h = (const float*)d_in[0];
  const int* adj = (const int*)d_in[1];
  const float* W = (const float*)d_in[2];
  float* out = (float*)d_out;

  const size_t SZ_P    = (size_t)NN * NN * 2;      // 134.2 MB
  const size_t SZ_MASK = (size_t)NN * NN / 8;      // 8.4 MB  (-> part0; mask itself unused now)
  const size_t SZ_WHT  = (size_t)DD * NN * 2;      // 8.4 MB
  const size_t SZ_HB   = (size_t)NN * DD * 2;      // 8.4 MB  (-> part2)
  const size_t SZ_WB   = (size_t)DD * DD * 2;      // 0.5 MB
  const size_t SZ_U    = (size_t)NN * DD * 2;      // 8.4 MB  (-> part1)
  const size_t SZ_P3   = (size_t)NN * DD * 2;      // 8.4 MB  (part3)
  const size_t NEEDED  = SZ_P + SZ_MASK + SZ_WHT + SZ_HB + SZ_WB + SZ_U + SZ_P3 + 2 * (size_t)NN * 4;

  if (ws_size < NEEDED) {
    fill_kernel<<<256, 256, 0, stream>>>(out, out_size, 12345.0f);
    return;
  }

  char* ws = (char*)d_ws;
  size_t off = 0;
  u16*   P    = (u16*)(ws + off); off += SZ_P;
  u16*   mask = (u16*)(ws + off); off += SZ_MASK;
  u16*   WhT  = (u16*)(ws + off); off += SZ_WHT;
  u16*   hb   = (u16*)(ws + off); off += SZ_HB;
  u16*   Wb   = (u16*)(ws + off); off += SZ_WB;
  u16*   U    = (u16*)(ws + off); off += SZ_U;
  u16*   p3   = (u16*)(ws + off); off += SZ_P3;
  float* invn = (float*)(ws + off);
  float* den  = invn + NN;

  // Wh fp32 (16.8 MB) aliases the P prefix: dead before sim writes P.
  float* Wh = (float*)P;
  // split-K partials reuse regions dead after the sim-GEMM:
  u16* part0 = mask;
  u16* part1 = U;
  u16* part2 = hb;
  u16* part3 = p3;

  cvt4_kernel<<<1024, 256, 0, stream>>>((const float4*)h, (ushort4*)hb, NN * DD / 4);
  cvt4_kernel<<<256, 256, 0, stream>>>((const float4*)W, (ushort4*)Wb, DD * DD / 4);
  // Wh = h @ W^T
  gemm_wh<<<dim3(DD / 128, NN / 128), 256, 0, stream>>>(hb, Wb, DD, DD, Wh);
  rownorm_kernel<<<NN, 64, 0, stream>>>(Wh, invn, den);
  u_wht_kernel<<<dim3(NN / 64, DD / 64), 256, 0, stream>>>(Wh, invn, U, WhT);
  // P = mask ? exp(U U^T) : 0 (bf16), symmetric lower-tri + mirror, fused den;
  // adj read directly (pack_adj pass eliminated)
  gemm_sim<<<64 * 65 / 2, 256, 0, stream>>>(U, adj, P, den);
  // out partials: 256x256 tile, phase-split counted-vmcnt schedule, split-K=4
  gemm_out2<<<dim3(NN / 256, DD / 256, 4), 512, 0, stream>>>(P, WhT, part0, part1, part2, part3);
  // out = (p0+p1+p2+p3) / den
  reduce4_kernel<<<NN * DD / 8 / 256, 256, 0, stream>>>(
      (const uint4*)part0, (const uint4*)part1, (const uint4*)part2, (const uint4*)part3,
      den, (float4*)out);
}

// Round 4
// 569.297 us; speedup vs baseline: 1.1427x; 1.0185x over previous
//
#include <hip/hip_runtime.h>
#include <hip/hip_bf16.h>
#include <stdint.h>

#define NN 8192
#define DD 512

typedef unsigned short u16;
typedef __attribute__((ext_vector_type(8))) short short8;
typedef __attribute__((ext_vector_type(4))) float f32x4;

// async global->LDS, 16B per lane; LDS dest = wave-uniform base + lane*16
__device__ __forceinline__ void gld_lds16(const void* g, void* l) {
  __builtin_amdgcn_global_load_lds(
      (const __attribute__((address_space(1))) uint32_t*)(uintptr_t)g,
      (__attribute__((address_space(3))) uint32_t*)(uintptr_t)l,
      16, 0, 0);
}

__device__ __forceinline__ u16 f2bf(float f) {
  __hip_bfloat16 b = __float2bfloat16(f);
  return __builtin_bit_cast(u16, b);
}

__global__ void fill_kernel(float* __restrict__ p, int n, float v) {
  int i = blockIdx.x * 256 + threadIdx.x;
  int stride = gridDim.x * 256;
  for (; i < n; i += stride) p[i] = v;
}

__global__ void cvt4_kernel(const float4* __restrict__ src, ushort4* __restrict__ dst, int n4) {
  int i = blockIdx.x * 256 + threadIdx.x;
  int stride = gridDim.x * 256;
  for (; i < n4; i += stride) {
    float4 v = src[i];
    ushort4 o;
    o.x = f2bf(v.x); o.y = f2bf(v.y); o.z = f2bf(v.z); o.w = f2bf(v.w);
    dst[i] = o;
  }
}

// one wave per row: 1/||Wh_i||; also zeroes den[row]
__global__ void rownorm_kernel(const float* __restrict__ Wh, float* __restrict__ invn,
                               float* __restrict__ den) {
  int row = blockIdx.x;
  int l = threadIdx.x;  // 64
  const float4* p = (const float4*)(Wh + (size_t)row * DD);
  float4 a = p[l], b = p[l + 64];
  float s = a.x*a.x + a.y*a.y + a.z*a.z + a.w*a.w
          + b.x*b.x + b.y*b.y + b.z*b.z + b.w*b.w;
  #pragma unroll
  for (int off = 32; off; off >>= 1) s += __shfl_down(s, off);
  if (l == 0) {
    invn[row] = 1.0f / sqrtf(s);
    den[row] = 0.0f;
  }
}

// 64x64 tile: U = bf16(Wh * invn) (row-major) and WhT = bf16(Wh)^T
__global__ void u_wht_kernel(const float* __restrict__ Wh, const float* __restrict__ invn,
                             u16* __restrict__ U, u16* __restrict__ WhT) {
  __shared__ float tile[64][65];
  int i0 = blockIdx.x * 64, d0 = blockIdx.y * 64;
  int c = threadIdx.x & 63, rb = threadIdx.x >> 6;
  #pragma unroll
  for (int r = rb; r < 64; r += 4) {
    float v = Wh[(size_t)(i0 + r) * DD + d0 + c];
    tile[r][c] = v;
    U[(size_t)(i0 + r) * DD + d0 + c] = f2bf(v * invn[i0 + r]);
  }
  __syncthreads();
  #pragma unroll
  for (int r = rb; r < 64; r += 4) {
    WhT[(size_t)(d0 + r) * NN + i0 + c] = f2bf(tile[c][r]);
  }
}

// Wh-GEMM: C = A * B^T fp32, A:[M x K], B:[Nn x K] bf16. 128x128 tile, 256 thr.
__global__ void __launch_bounds__(256) gemm_wh(
    const u16* __restrict__ A, const u16* __restrict__ B,
    int Nn, int K, float* __restrict__ Cf)
{
  __shared__ __align__(16) u16 As[128 * 32];
  __shared__ __align__(16) u16 Bs[128 * 32];

  const int tid = threadIdx.x;
  const int w = tid >> 6;
  const int lane = tid & 63;
  const int lm = lane & 15;
  const int q = lane >> 4;
  const int row0 = blockIdx.y * 128;
  const int col0 = blockIdx.x * 128;
  const int RM = (w >> 1) * 64;
  const int RN = (w & 1) * 64;
  const int sr = tid >> 2;
  const int sk = (tid & 3) * 8;

  f32x4 acc[4][4];
  #pragma unroll
  for (int a_ = 0; a_ < 4; a_++)
    #pragma unroll
    for (int b_ = 0; b_ < 4; b_++)
      acc[a_][b_] = (f32x4){0.f, 0.f, 0.f, 0.f};

  const size_t Abase = (size_t)row0 * K;
  const size_t Bbase = (size_t)col0 * K;

  for (int k0 = 0; k0 < K; k0 += 32) {
    __syncthreads();
    gld_lds16(A + Abase + (size_t)sr * K + k0 + sk,        (char*)As + w * 1024);
    gld_lds16(A + Abase + (size_t)(sr + 64) * K + k0 + sk, (char*)As + 4096 + w * 1024);
    gld_lds16(B + Bbase + (size_t)sr * K + k0 + sk,        (char*)Bs + w * 1024);
    gld_lds16(B + Bbase + (size_t)(sr + 64) * K + k0 + sk, (char*)Bs + 4096 + w * 1024);
    __syncthreads();

    short8 af[4], bfr[4];
    #pragma unroll
    for (int mt = 0; mt < 4; mt++)
      af[mt] = *(const short8*)&As[(RM + mt * 16 + lm) * 32 + q * 8];
    #pragma unroll
    for (int nt = 0; nt < 4; nt++)
      bfr[nt] = *(const short8*)&Bs[(RN + nt * 16 + lm) * 32 + q * 8];

    #pragma unroll
    for (int mt = 0; mt < 4; mt++)
      #pragma unroll
      for (int nt = 0; nt < 4; nt++)
        acc[mt][nt] = __builtin_amdgcn_mfma_f32_16x16x32_bf16(af[mt], bfr[nt], acc[mt][nt], 0, 0, 0);
  }

  #pragma unroll
  for (int mt = 0; mt < 4; mt++) {
    const int ib = row0 + RM + mt * 16 + q * 4;
    #pragma unroll
    for (int rr = 0; rr < 4; rr++) {
      const int i = ib + rr;
      #pragma unroll
      for (int nt = 0; nt < 4; nt++) {
        const int jc = col0 + RN + nt * 16 + lm;
        Cf[(size_t)i * Nn + jc] = acc[mt][nt][rr];
      }
    }
  }
}

// sim-GEMM v4: FULL grid (64x64 blocks, no lower-tri mirror). Each block computes
// its own 128x128 S tile and writes only its own P tile (coalesced 32B chunks).
// This deletes the mirror path (scattered ushort4 stores across 64 rows/instr,
// mirror uint4 adj loads, msum + mirror atomics) that dominated v3's epilogue
// (183us, MfmaUtil 7.4%, all pipes idle = latency-bound epilogue). MFMA doubles
// but 4096 light blocks overlap mains/epilogues far better than 2080 heavy ones.
// adj batch-0 is prefetched BEFORE the prologue (oldest in vmcnt order -> retires
// with tile-0's stage; consumed ~3us later = free latency hiding); epilogue
// pipelines adj batches 1-deep with statically-named register sets.
__global__ void __launch_bounds__(256) gemm_sim(
    const u16* __restrict__ U, const int* __restrict__ adj,
    u16* __restrict__ Pb, float* __restrict__ den)
{
  __shared__ __align__(16) char lds[32768];  // buf b at b*16384: A 8KB | B 8KB

  const int bj = blockIdx.x;
  const int bi = blockIdx.y;

  const int tid = threadIdx.x;
  const int w = tid >> 6;
  const int lane = tid & 63;
  const int lm = lane & 15;
  const int q = lane >> 4;
  const int row0 = bi * 128;
  const int col0 = bj * 128;
  const int RM = (w >> 1) * 64;
  const int RN = (w & 1) * 64;
  const bool diag = (bi == bj);

  const u16* Ab = U + (size_t)row0 * DD;
  const u16* Bb = U + (size_t)col0 * DD;

  // staging: 256 threads cover 64 rows per gld (row tid>>2, slot tid&3);
  // source content chunk = slot ^ ((row>>1)&3)  (row>>1 == tid>>3)
  const int srow = tid >> 2;                                  // 0..63
  const int sch8 = (((tid & 3) ^ ((tid >> 3) & 3)) << 3);     // element offset
  const int wofs = w << 10;                                   // per-wave LDS base

  // read-side: logical (r, chunk c) lives at byte r*64 + ((c ^ ((r>>1)&3))<<4);
  // (r>>1)&3 invariant under r += 16, fold once.
  const int rA = RM + lm;
  const int rB = RN + lm;
  const int aoff = rA * 64 + ((q ^ ((rA >> 1) & 3)) << 4);
  const int boff = 8192 + rB * 64 + ((q ^ ((rB >> 1) & 3)) << 4);

  f32x4 acc[4][4];
  #pragma unroll
  for (int a_ = 0; a_ < 4; a_++)
    #pragma unroll
    for (int b_ = 0; b_ < 4; b_++)
      acc[a_][b_] = (f32x4){0.f, 0.f, 0.f, 0.f};

  // ---- adj prefetch: batch mt=0 issued FIRST (oldest VMEM ops). The prologue
  // vmcnt(4) below then waits for {these 16} + {tile0's 4 stages}, leaving
  // tile1's 4 in flight -- semantics unchanged, adj latency fully hidden.
  int na0[4][4], na1[4][4];
  {
    const int ib0 = row0 + RM + q * 4;
    #pragma unroll
    for (int rr = 0; rr < 4; rr++)
      #pragma unroll
      for (int nt = 0; nt < 4; nt++)
        na0[rr][nt] = adj[(size_t)(ib0 + rr) * NN + col0 + RN + nt * 16 + lm];
  }
  asm volatile("" ::: "memory");  // pin adj loads before the staging stream

#define SSTAGE(koff, dstoff)                                                      \
  do {                                                                            \
    char* d_ = lds + (dstoff);                                                    \
    gld_lds16(Ab + (size_t)srow * DD + (koff) + sch8,        d_ + wofs);          \
    gld_lds16(Ab + (size_t)(srow + 64) * DD + (koff) + sch8, d_ + 4096 + wofs);   \
    gld_lds16(Bb + (size_t)srow * DD + (koff) + sch8,        d_ + 8192 + wofs);   \
    gld_lds16(Bb + (size_t)(srow + 64) * DD + (koff) + sch8, d_ + 12288 + wofs);  \
  } while (0)

  // prologue: tile 0 -> buf0, tile 1 -> buf1; drain adj batch0 + tile 0,
  // leave tile 1 in flight
  SSTAGE(0, 0);
  SSTAGE(32, 16384);
  asm volatile("s_waitcnt vmcnt(4)" ::: "memory");
  asm volatile("s_barrier" ::: "memory");

#define STILE(T, CBOFF)                                                           \
  do {                                                                            \
    const char* cb = lds + (CBOFF);                                               \
    short8 af[4], bfr[4];                                                         \
    _Pragma("unroll")                                                             \
    for (int m = 0; m < 4; m++)                                                   \
      af[m] = *(const short8*)(cb + aoff + m * 1024);                             \
    _Pragma("unroll")                                                             \
    for (int n = 0; n < 4; n++)                                                   \
      bfr[n] = *(const short8*)(cb + boff + n * 1024);                            \
    asm volatile("s_barrier" ::: "memory");                                       \
    asm volatile("s_waitcnt lgkmcnt(0)" ::: "memory");                            \
    __builtin_amdgcn_s_setprio(1);                                                \
    _Pragma("unroll")                                                             \
    for (int m = 0; m < 2; m++)                                                   \
      _Pragma("unroll")                                                           \
      for (int n = 0; n < 4; n++)                                                 \
        acc[m][n] = __builtin_amdgcn_mfma_f32_16x16x32_bf16(af[m], bfr[n], acc[m][n], 0, 0, 0); \
    __builtin_amdgcn_s_setprio(0);                                                \
    asm volatile("s_barrier" ::: "memory");                                       \
    if ((T) + 2 < 16) SSTAGE(((T) + 2) * 32, CBOFF);                              \
    asm volatile("s_barrier" ::: "memory");                                       \
    __builtin_amdgcn_s_setprio(1);                                                \
    _Pragma("unroll")                                                             \
    for (int m = 2; m < 4; m++)                                                   \
      _Pragma("unroll")                                                           \
      for (int n = 0; n < 4; n++)                                                 \
        acc[m][n] = __builtin_amdgcn_mfma_f32_16x16x32_bf16(af[m], bfr[n], acc[m][n], 0, 0, 0); \
    __builtin_amdgcn_s_setprio(0);                                                \
    if ((T) + 2 < 16) { asm volatile("s_waitcnt vmcnt(4)" ::: "memory"); }        \
    else              { asm volatile("s_waitcnt vmcnt(0)" ::: "memory"); }        \
    asm volatile("s_barrier" ::: "memory");                                       \
  } while (0)

  #pragma unroll 1
  for (int t = 0; t < 16; t += 2) {
    STILE(t, 0);
    STILE(t + 1, 16384);
  }
#undef STILE
#undef SSTAGE

  // ---- epilogue: C/D layout col = lm, row = q*4 + rr. adj batches pipelined
  // 1-deep: issue batch MT+1's loads, then process batch MT from registers.
#define EPI(MT, NAC, NAN, DOLOAD)                                                 \
  do {                                                                            \
    if (DOLOAD) {                                                                 \
      const int ibn = row0 + RM + ((MT) + 1) * 16 + q * 4;                        \
      _Pragma("unroll")                                                           \
      for (int rr = 0; rr < 4; rr++)                                              \
        _Pragma("unroll")                                                         \
        for (int nt = 0; nt < 4; nt++)                                            \
          NAN[rr][nt] = adj[(size_t)(ibn + rr) * NN + col0 + RN + nt * 16 + lm];  \
    }                                                                             \
    const int ibc = row0 + RM + (MT) * 16 + q * 4;                                \
    _Pragma("unroll")                                                             \
    for (int rr = 0; rr < 4; rr++) {                                              \
      const int i = ibc + rr;                                                     \
      float psum = 0.f;                                                           \
      _Pragma("unroll")                                                           \
      for (int nt = 0; nt < 4; nt++) {                                            \
        const int jc = col0 + RN + nt * 16 + lm;                                  \
        const float ev = __expf(acc[MT][nt][rr]);                                 \
        const bool on = (NAC[rr][nt] != 0) || (diag && i == jc);                  \
        const float p = on ? ev : 0.0f;                                           \
        psum += p;                                                                \
        Pb[(size_t)i * NN + jc] = f2bf(p);                                        \
      }                                                                           \
      _Pragma("unroll")                                                           \
      for (int off = 8; off; off >>= 1) psum += __shfl_down(psum, off, 16);       \
      if (lm == 0) atomicAdd(&den[i], psum);                                      \
    }                                                                             \
  } while (0)

  EPI(0, na0, na1, 1);
  EPI(1, na1, na0, 1);
  EPI(2, na0, na1, 1);
  EPI(3, na1, na0, 0);
#undef EPI
}

// out-GEMM v2: 256x256 tile, BK=32, 8 waves (2M x 4N), split-K=4 via blockIdx.z.
// Phase-split schedule (T3/T4): per K-tile two phases, counted s_waitcnt vmcnt(4)
// (tile t+2's 4 staging loads stay in flight across barriers, never drained to 0
// in steady state), XOR chunk swizzle (T2: slot = c ^ ((r>>1)&3), pre-swizzled
// global source + swizzled ds_read -> 2-way conflicts = free), setprio around
// each 16-MFMA cluster (T5). 64 KB LDS double-buffer (2 x 32 KB K-tile buffers).
__global__ void __launch_bounds__(512, 2) gemm_out2(
    const u16* __restrict__ P_,   // P [NN x NN]
    const u16* __restrict__ Wt,   // WhT [DD x NN]
    u16* __restrict__ p0, u16* __restrict__ p1,
    u16* __restrict__ p2, u16* __restrict__ p3)
{
  __shared__ __align__(16) char lds[65536];  // buf b at b*32768: A 16KB | B 16KB

  const int tid = threadIdx.x;
  const int lane = tid & 63;
  const int lm = lane & 15;
  const int q = lane >> 4;
  const int w = tid >> 6;       // 0..7
  const int wm = w >> 2;        // 0..1 -> 128 rows
  const int wn = w & 3;         // 0..3 -> 64 cols
  const int row0 = blockIdx.x * 256;   // i block
  const int col0 = blockIdx.y * 256;   // d block
  const int z = blockIdx.z;            // split-K
  const int kBegin = z * (NN / 4);
  const int NT = (NN / 4) / 32;        // 64 K-tiles

  const u16* Ab = P_ + (size_t)row0 * NN;
  const u16* Bb = Wt + (size_t)col0 * NN;

  // staging: 512 threads cover one 128-row half per gld (rows tid>>2, slot tid&3).
  // content chunk = slot ^ ((row>>1)&3)  (inverse of the read-side swizzle)
  const int srow = tid >> 2;                                  // 0..127
  const int sch8 = (((tid & 3) ^ ((tid >> 3) & 3)) << 3);     // element offset
  const int wofs = (tid >> 6) << 10;                          // per-wave LDS base

  // read-side: logical (r, chunk c) lives at byte r*64 + ((c ^ ((r>>1)&3))<<4).
  // (r>>1)&3 is invariant under r += 16, so fold it once.
  const int rA = wm * 128 + lm;
  const int rB = wn * 64 + lm;
  const int aoff = rA * 64 + ((q ^ ((rA >> 1) & 3)) << 4);
  const int boff = 16384 + rB * 64 + ((q ^ ((rB >> 1) & 3)) << 4);

  f32x4 acc[8][4];
  #pragma unroll
  for (int m = 0; m < 8; m++)
    #pragma unroll
    for (int n = 0; n < 4; n++)
      acc[m][n] = (f32x4){0.f, 0.f, 0.f, 0.f};

#define STAGE4(koff, dstoff)                                                      \
  do {                                                                            \
    char* d_ = lds + (dstoff);                                                    \
    gld_lds16(Ab + (size_t)srow * NN + (koff) + sch8,         d_ + wofs);         \
    gld_lds16(Ab + (size_t)(srow + 128) * NN + (koff) + sch8, d_ + 8192 + wofs);  \
    gld_lds16(Bb + (size_t)srow * NN + (koff) + sch8,         d_ + 16384 + wofs); \
    gld_lds16(Bb + (size_t)(srow + 128) * NN + (koff) + sch8, d_ + 24576 + wofs); \
  } while (0)

  // prologue: tile 0 -> buf0, tile 1 -> buf1; drain tile 0, leave tile 1 in flight
  STAGE4(kBegin, 0);
  STAGE4(kBegin + 32, 32768);
  asm volatile("s_waitcnt vmcnt(4)" ::: "memory");
  asm volatile("s_barrier" ::: "memory");

#define TILE(T, CBOFF)                                                            \
  do {                                                                            \
    const char* cb = lds + (CBOFF);                                               \
    short8 af[8], bf_[4];                                                         \
    _Pragma("unroll")                                                             \
    for (int m = 0; m < 8; m++)                                                   \
      af[m] = *(const short8*)(cb + aoff + m * 1024);                             \
    _Pragma("unroll")                                                             \
    for (int n = 0; n < 4; n++)                                                   \
      bf_[n] = *(const short8*)(cb + boff + n * 1024);                            \
    asm volatile("s_barrier" ::: "memory");                                       \
    asm volatile("s_waitcnt lgkmcnt(0)" ::: "memory");                            \
    __builtin_amdgcn_s_setprio(1);                                                \
    _Pragma("unroll")                                                             \
    for (int m = 0; m < 4; m++)                                                   \
      _Pragma("unroll")                                                           \
      for (int n = 0; n < 4; n++)                                                 \
        acc[m][n] = __builtin_amdgcn_mfma_f32_16x16x32_bf16(af[m], bf_[n], acc[m][n], 0, 0, 0); \
    __builtin_amdgcn_s_setprio(0);                                                \
    asm volatile("s_barrier" ::: "memory");                                       \
    if ((T) + 2 < NT) STAGE4(kBegin + ((T) + 2) * 32, CBOFF);                     \
    asm volatile("s_barrier" ::: "memory");                                       \
    __builtin_amdgcn_s_setprio(1);                                                \
    _Pragma("unroll")                                                             \
    for (int m = 4; m < 8; m++)                                                   \
      _Pragma("unroll")                                                           \
      for (int n = 0; n < 4; n++)                                                 \
        acc[m][n] = __builtin_amdgcn_mfma_f32_16x16x32_bf16(af[m], bf_[n], acc[m][n], 0, 0, 0); \
    __builtin_amdgcn_s_setprio(0);                                                \
    if ((T) + 2 < NT) { asm volatile("s_waitcnt vmcnt(4)" ::: "memory"); }        \
    else              { asm volatile("s_waitcnt vmcnt(0)" ::: "memory"); }        \
    asm volatile("s_barrier" ::: "memory");                                       \
  } while (0)

  #pragma unroll 1
  for (int t = 0; t < NT; t += 2) {
    TILE(t, 0);
    TILE(t + 1, 32768);
  }
#undef TILE
#undef STAGE4

  u16* const part = (z == 0) ? p0 : (z == 1) ? p1 : (z == 2) ? p2 : p3;
  #pragma unroll
  for (int m = 0; m < 8; m++) {
    const int ib = row0 + wm * 128 + m * 16 + q * 4;
    #pragma unroll
    for (int rr = 0; rr < 4; rr++) {
      const int i = ib + rr;
      #pragma unroll
      for (int n = 0; n < 4; n++) {
        const int dc = col0 + wn * 64 + n * 16 + lm;
        part[(size_t)i * DD + dc] = f2bf(acc[m][n][rr]);
      }
    }
  }
}

// out = (sum of 4 bf16 partials) / den[row]; each thread handles 8 cols
__global__ void reduce4_kernel(const uint4* __restrict__ p0, const uint4* __restrict__ p1,
                               const uint4* __restrict__ p2, const uint4* __restrict__ p3,
                               const float* __restrict__ den, float4* __restrict__ out) {
  const int idx = blockIdx.x * 256 + threadIdx.x;   // NN*DD/8 units of 8 cols
  const int row = idx >> 6;                          // 64 units per row
  const float dinv = 1.0f / den[row];
  float s[8] = {0, 0, 0, 0, 0, 0, 0, 0};
  #pragma unroll
  for (int zp = 0; zp < 4; zp++) {
    const uint4 u = (zp == 0 ? p0 : zp == 1 ? p1 : zp == 2 ? p2 : p3)[idx];
    s[0] += __uint_as_float(u.x << 16); s[1] += __uint_as_float(u.x & 0xffff0000u);
    s[2] += __uint_as_float(u.y << 16); s[3] += __uint_as_float(u.y & 0xffff0000u);
    s[4] += __uint_as_float(u.z << 16); s[5] += __uint_as_float(u.z & 0xffff0000u);
    s[6] += __uint_as_float(u.w << 16); s[7] += __uint_as_float(u.w & 0xffff0000u);
  }
  float4 o0 = {s[0] * dinv, s[1] * dinv, s[2] * dinv, s[3] * dinv};
  float4 o1 = {s[4] * dinv, s[5] * dinv, s[6] * dinv, s[7] * dinv};
  out[idx * 2] = o0;
  out[idx * 2 + 1] = o1;
}

extern "C" void kernel_launch(void* const* d_in, const int* in_sizes, int n_in,
                              void* d_out, int out_size, void* d_ws, size_t ws_size,
                              hipStream_t stream) {
  const float* h = (const float*)d_in[0];
  const int* adj = (const int*)d_in[1];
  const float* W = (const float*)d_in[2];
  float* out = (float*)d_out;

  const size_t SZ_P    = (size_t)NN * NN * 2;      // 134.2 MB
  const size_t SZ_X0   = (size_t)NN * NN / 8;      // 8.4 MB  (-> part0)
  const size_t SZ_WHT  = (size_t)DD * NN * 2;      // 8.4 MB
  const size_t SZ_HB   = (size_t)NN * DD * 2;      // 8.4 MB  (-> part2)
  const size_t SZ_WB   = (size_t)DD * DD * 2;      // 0.5 MB
  const size_t SZ_U    = (size_t)NN * DD * 2;      // 8.4 MB  (-> part1)
  const size_t SZ_P3   = (size_t)NN * DD * 2;      // 8.4 MB  (part3)
  const size_t NEEDED  = SZ_P + SZ_X0 + SZ_WHT + SZ_HB + SZ_WB + SZ_U + SZ_P3 + 2 * (size_t)NN * 4;

  if (ws_size < NEEDED) {
    fill_kernel<<<256, 256, 0, stream>>>(out, out_size, 12345.0f);
    return;
  }

  char* ws = (char*)d_ws;
  size_t off = 0;
  u16*   P    = (u16*)(ws + off); off += SZ_P;
  u16*   x0   = (u16*)(ws + off); off += SZ_X0;
  u16*   WhT  = (u16*)(ws + off); off += SZ_WHT;
  u16*   hb   = (u16*)(ws + off); off += SZ_HB;
  u16*   Wb   = (u16*)(ws + off); off += SZ_WB;
  u16*   U    = (u16*)(ws + off); off += SZ_U;
  u16*   p3   = (u16*)(ws + off); off += SZ_P3;
  float* invn = (float*)(ws + off);
  float* den  = invn + NN;

  // Wh fp32 (16.8 MB) aliases the P prefix: dead before sim writes P.
  float* Wh = (float*)P;
  // split-K partials reuse regions dead after the sim-GEMM:
  u16* part0 = x0;
  u16* part1 = U;
  u16* part2 = hb;
  u16* part3 = p3;

  cvt4_kernel<<<1024, 256, 0, stream>>>((const float4*)h, (ushort4*)hb, NN * DD / 4);
  cvt4_kernel<<<256, 256, 0, stream>>>((const float4*)W, (ushort4*)Wb, DD * DD / 4);
  // Wh = h @ W^T
  gemm_wh<<<dim3(DD / 128, NN / 128), 256, 0, stream>>>(hb, Wb, DD, DD, Wh);
  rownorm_kernel<<<NN, 64, 0, stream>>>(Wh, invn, den);
  u_wht_kernel<<<dim3(NN / 64, DD / 64), 256, 0, stream>>>(Wh, invn, U, WhT);
  // P = mask ? exp(U U^T) : 0 (bf16), full grid (each block owns its tile), fused den
  gemm_sim<<<dim3(NN / 128, NN / 128), 256, 0, stream>>>(U, adj, P, den);
  // out partials: 256x256 tile, phase-split counted-vmcnt schedule, split-K=4
  gemm_out2<<<dim3(NN / 256, DD / 256, 4), 512, 0, stream>>>(P, WhT, part0, part1, part2, part3);
  // out = (p0+p1+p2+p3) / den
  reduce4_kernel<<<NN * DD / 8 / 256, 256, 0, stream>>>(
      (const uint4*)part0, (const uint4*)part1, (const uint4*)part2, (const uint4*)part3,
      den, (float4*)out);
}